// Round 1
// 1446.834 us; speedup vs baseline: 2.9296x; 2.9296x over previous
//
#include <hip/hip_runtime.h>
#include <math.h>

// ============================================================================
// SPDNet forward, eig-free — v2: all 64x64 matmuls moved from f32 VALU to
// f16 MFMA (v_mfma_f32_16x16x32_f16) with split-f16 emulation of fp32:
//   v = hi + lo/4096 (hi,lo f16); L*R = hi*hi + (hi*lo' + lo'*hi)/4096
// (3 MFMAs, f32 accumulate) -> ~2^-22 relative accuracy (fp32-class).
// Matrices live in LDS as two XOR-swizzled f16 planes (8KB each, 4 slots =
// 64KB). Convention: each plane stores the TRANSPOSE of its semantic matrix
// (free: the MFMA D-fragment is column-contiguous -> natural b64 store is the
// transposed store). Then mmA(L,R) = L^T * R with row-major fragment reads for
// both operands — identical semantics to the old VALU mm64 (left operands in
// the pipeline are all symmetric).
// ============================================================================

#define NS_IT   7
#define NSC_IT  12
#define C1      0.0038729833f
#define LNC1    (-5.553730f)
#define SPLIT_S 4096.f
#define SPLIT_R (1.f/4096.f)

typedef _Float16 h16;
typedef _Float16 h16x8 __attribute__((ext_vector_type(8)));
typedef _Float16 h16x4 __attribute__((ext_vector_type(4)));
typedef float    f32x4 __attribute__((ext_vector_type(4)));

// ws layout (floats)
#define WS_S1   ((size_t)0)
#define WS_R2   ((size_t)8388608)
#define WS_SM   ((size_t)16777216)
#define SM_LBAR  0
#define SM_EBAR1 4096
#define SM_EBAR2 8192
#define SM_GI0   12288
#define SM_GS0   16384
#define SM_GI1   20480
#define SM_GS1   24576
#define SM_GI2   28672
#define SM_GS2   32768
#define SM_BS    36864
#define SM_VPART 40960
#define SM_S     40992

__device__ __forceinline__ float4 ld4(const float* p){ return *(const float4*)p; }
__device__ __forceinline__ void  st4(float* p, float4 v){ *(float4*)p = v; }

// ---------------- split-f16 plane helpers ----------------
// plane: 64x64 f16, element (r,c) at byte (r*128 + c*2) ^ ((r&7)<<4)
__device__ __forceinline__ int eoff(int r, int c){ return (r*128 + c*2) ^ ((r&7)<<4); }

__device__ __forceinline__ h16x8 frag_ld(const h16* p, int row, int ks, int lg){
  int off = (row*128 + ks*64 + lg*16) ^ ((row&7)<<4);
  return *(const h16x8*)((const char*)p + off);
}
__device__ __forceinline__ h16x4 h4_ld(const h16* p, int r, int c4){
  return *(const h16x4*)((const char*)p + eoff(r,c4));
}
__device__ __forceinline__ void h4_st(h16* p, int r, int c4, h16x4 v){
  *(h16x4*)((char*)p + eoff(r,c4)) = v;
}
__device__ __forceinline__ void split2(float v, h16& h, h16& l){
  h16 hh = (h16)v;
  h = hh;
  l = (h16)((v - (float)hh) * SPLIT_S);
}
__device__ __forceinline__ float join2(h16 h, h16 l){
  return (float)h + (float)l * SPLIT_R;
}

// ---------------- MFMA 64x64x64: D = L^T * R (planes store transposes) ------
template<int GP>
__device__ __forceinline__ void mmA_t(const h16* Lh, const h16* Ll,
                                      const h16* Rh, const h16* Rl,
                                      const h16* gR,
                                      f32x4 acc[2][2], int lane, int wv){
  int lr = lane&15, lg = lane>>4;
  int rb = (wv&1)*32, cb = (wv>>1)*32;
  h16x8 a[2][2][2];                       // [rt][ks][hi/lo]
  #pragma unroll
  for(int rt=0;rt<2;rt++)
    #pragma unroll
    for(int ks=0;ks<2;ks++){
      a[rt][ks][0] = frag_ld(Lh, rb+16*rt+lr, ks, lg);
      a[rt][ks][1] = frag_ld(Ll, rb+16*rt+lr, ks, lg);
    }
  f32x4 aM[2][2], aC[2][2];
  const f32x4 vz = {0.f,0.f,0.f,0.f};
  #pragma unroll
  for(int rt=0;rt<2;rt++)
    #pragma unroll
    for(int ct=0;ct<2;ct++){ aM[rt][ct]=vz; aC[rt][ct]=vz; }
  #pragma unroll
  for(int ct=0;ct<2;ct++){
    #pragma unroll
    for(int ks=0;ks<2;ks++){
      h16x8 bh, bl;
      if (GP){
        const h16* g = gR + (cb+16*ct+lr)*64 + ks*32 + lg*8;
        bh = *(const h16x8*)g;
        bl = *(const h16x8*)(g + 4096);
      } else {
        bh = frag_ld(Rh, cb+16*ct+lr, ks, lg);
        bl = frag_ld(Rl, cb+16*ct+lr, ks, lg);
      }
      #pragma unroll
      for(int rt=0;rt<2;rt++){
        aM[rt][ct] = __builtin_amdgcn_mfma_f32_16x16x32_f16(a[rt][ks][0], bh, aM[rt][ct], 0,0,0);
        aC[rt][ct] = __builtin_amdgcn_mfma_f32_16x16x32_f16(a[rt][ks][0], bl, aC[rt][ct], 0,0,0);
        aC[rt][ct] = __builtin_amdgcn_mfma_f32_16x16x32_f16(a[rt][ks][1], bh, aC[rt][ct], 0,0,0);
      }
    }
  }
  #pragma unroll
  for(int rt=0;rt<2;rt++)
    #pragma unroll
    for(int ct=0;ct<2;ct++)
      acc[rt][ct] = aM[rt][ct] + aC[rt][ct]*SPLIT_R;
}

__device__ __forceinline__ void mmA(const h16* Lh,const h16* Ll,const h16* Rh,const h16* Rl,
                                    f32x4 acc[2][2], int lane,int wv){
  mmA_t<0>(Lh,Ll,Rh,Rl,(const h16*)0,acc,lane,wv);
}
__device__ __forceinline__ void mmA_g(const h16* Lh,const h16* Ll,const h16* gR,
                                      f32x4 acc[2][2], int lane,int wv){
  mmA_t<1>(Lh,Ll,(const h16*)0,(const h16*)0,gR,acc,lane,wv);
}

// store D (f32 regs) into planes, transposed, with scale/diag-add
__device__ __forceinline__ void st_mm(h16* Dh, h16* Dl, const f32x4 acc[2][2],
                                      int lane,int wv, float scale, float dadd){
  int lr=lane&15, lg=lane>>4;
  int rb=(wv&1)*32, cb=(wv>>1)*32;
  #pragma unroll
  for(int rt=0;rt<2;rt++){
    int i0 = rb+16*rt+lg*4;
    #pragma unroll
    for(int ct=0;ct<2;ct++){
      int j = cb+16*ct+lr;
      h16x4 h4, l4;
      #pragma unroll
      for(int r=0;r<4;r++){
        float x = acc[rt][ct][r]*scale;
        if (i0+r==j) x += dadd;
        h16 hh,ll; split2(x,hh,ll);
        h4[r]=hh; l4[r]=ll;
      }
      int off = (j*128 + i0*2) ^ ((j&7)<<4);
      *(h16x4*)((char*)Dh + off) = h4;
      *(h16x4*)((char*)Dl + off) = l4;
    }
  }
}

// store D to global f32 (plane layout = transpose; outputs here are symmetric)
__device__ __forceinline__ void st_gl(float* G, const f32x4 acc[2][2],
                                      int lane,int wv,float scale,float dadd){
  int lr=lane&15, lg=lane>>4, rb=(wv&1)*32, cb=(wv>>1)*32;
  #pragma unroll
  for(int rt=0;rt<2;rt++){
    int i0=rb+16*rt+lg*4;
    #pragma unroll
    for(int ct=0;ct<2;ct++){
      int j=cb+16*ct+lr;
      float4 v; float* vf=(float*)&v;
      #pragma unroll
      for(int r=0;r<4;r++){
        float x=acc[rt][ct][r]*scale;
        if (i0+r==j) x += dadd;
        vf[r]=x;
      }
      st4(G + j*64 + i0, v);
    }
  }
}

// park D to global as split-f16 pair (hi plane at gh, lo at gh+4096), linear
__device__ __forceinline__ void st_park(h16* gh, const f32x4 acc[2][2], int lane,int wv){
  int lr=lane&15, lg=lane>>4, rb=(wv&1)*32, cb=(wv>>1)*32;
  #pragma unroll
  for(int rt=0;rt<2;rt++){
    int i0=rb+16*rt+lg*4;
    #pragma unroll
    for(int ct=0;ct<2;ct++){
      int j=cb+16*ct+lr;
      h16x4 h4,l4;
      #pragma unroll
      for(int r=0;r<4;r++){ h16 hh,ll; split2(acc[rt][ct][r],hh,ll); h4[r]=hh; l4[r]=ll; }
      *(h16x4*)(gh + j*64 + i0) = h4;
      *(h16x4*)(gh + 4096 + j*64 + i0) = l4;
    }
  }
}

// acc += a0*I + a1*S + a2*S2   (element-wise read of planes at D positions)
__device__ __forceinline__ void addq2(f32x4 acc[2][2],
    const h16* Sh, const h16* Sl, const h16* S2h, const h16* S2l,
    int lane, int wv, float a0, float a1, float a2){
  int lr=lane&15, lq=lane>>4;
  int rb=(wv&1)*32, cb=(wv>>1)*32;
  #pragma unroll
  for(int rt=0;rt<2;rt++){
    int i0=rb+16*rt+lq*4;
    #pragma unroll
    for(int ct=0;ct<2;ct++){
      int j=cb+16*ct+lr;
      h16x4 sh=h4_ld(Sh,j,i0), sl=h4_ld(Sl,j,i0);
      h16x4 th=h4_ld(S2h,j,i0), tl=h4_ld(S2l,j,i0);
      #pragma unroll
      for(int r=0;r<4;r++){
        float add = a1*join2(sh[r],sl[r]) + a2*join2(th[r],tl[r]);
        if (i0+r==j) add += a0;
        acc[rt][ct][r] += add;
      }
    }
  }
}

// fill planes from global f32 row-major symmetric: x = (v + dshift_on_diag)*scale
__device__ __forceinline__ void fill_gl(h16* Ph, h16* Pl, const float* g,
                                        float scale, float dshift, int tid){
  int r = tid>>2;
  #pragma unroll
  for(int q=0;q<4;q++){
    int c4 = (tid&3)*16 + q*4;
    float4 v = ld4(g + r*64 + c4);
    float vv[4]={v.x,v.y,v.z,v.w};
    h16x4 h4,l4;
    #pragma unroll
    for(int j=0;j<4;j++){
      float x = vv[j];
      if (c4+j == r) x += dshift;
      x *= scale;
      h16 hh,ll; split2(x,hh,ll); h4[j]=hh; l4[j]=ll;
    }
    h4_st(Ph,r,c4,h4); h4_st(Pl,r,c4,l4);
  }
}

__device__ __forceinline__ void plane_out(const h16* Ph, const h16* Pl, float* g,
                                          float scale, int tid){
  int r=tid>>2;
  #pragma unroll
  for(int q=0;q<4;q++){
    int c4=(tid&3)*16+q*4;
    h16x4 h4=h4_ld(Ph,r,c4), l4=h4_ld(Pl,r,c4);
    float4 v;
    v.x=join2(h4[0],l4[0])*scale;
    v.y=join2(h4[1],l4[1])*scale;
    v.z=join2(h4[2],l4[2])*scale;
    v.w=join2(h4[3],l4[3])*scale;
    st4(g + r*64 + c4, v);
  }
}

__device__ __forceinline__ void diag_add(h16* Ph, h16* Pl, float add, int tid){
  if (tid<64){
    int off = (tid*128 + tid*2) ^ ((tid&7)<<4);
    h16* ph = (h16*)((char*)Ph + off);
    h16* pl = (h16*)((char*)Pl + off);
    float v = join2(*ph,*pl) + add;
    h16 hh,ll; split2(v,hh,ll);
    *ph=hh; *pl=ll;
  }
}

__device__ float block_sum(float v, float* red, int tid){
  red[tid]=v; __syncthreads();
  for(int off=128; off>0; off>>=1){
    if (tid<off) red[tid]+=red[tid+off];
    __syncthreads();
  }
  float r=red[0]; __syncthreads();
  return r;
}

// old-layout global f32 store (kA phase-1 tx/ty decomposition)
__device__ __forceinline__ void st64(float* Cd, const float acc[4][4], int tx,int ty,
                                     float scale, float dadd){
  #pragma unroll
  for(int r=0;r<4;r++){
    float4 v; float* vf=(float*)&v;
    #pragma unroll
    for(int c=0;c<4;c++){
      float x = acc[r][c]*scale;
      if (ty==tx && r==c) x += dadd;
      vf[c]=x;
    }
    st4(Cd + (4*ty+r)*64 + 4*tx, v);
  }
}

// ---------------- Newton-Schulz inverse (MFMA) ----------------
__device__ void ns_inv2(h16* Ah, h16* Al, h16* Xh, h16* Xl, h16* Th, h16* Tl,
                        float* red, int tid,int lane,int wv, float lminB){
  {
    int row=tid>>2, seg=tid&3;
    float s=0.f;
    #pragma unroll
    for(int q=0;q<4;q++){
      h16x4 h4 = h4_ld(Ah,row,seg*16+q*4);
      #pragma unroll
      for(int j=0;j<4;j++) s += fabsf((float)h4[j]);
    }
    red[tid]=s*1.001f; __syncthreads();
    if((tid&3)==0) red[tid]=red[tid]+red[tid+1]+red[tid+2]+red[tid+3];
    __syncthreads();
    if(tid==0){ float m=0.f; for(int i=0;i<64;i++) m=fmaxf(m,red[4*i]); red[0]=m; }
    __syncthreads();
  }
  float alpha = 2.f/(lminB + red[0]);
  {
    int r=tid>>2;
    h16 ah,al_; split2(alpha,ah,al_);
    #pragma unroll
    for(int q=0;q<4;q++){
      int c4=(tid&3)*16+q*4;
      h16x4 h4={(h16)0,(h16)0,(h16)0,(h16)0};
      h16x4 l4={(h16)0,(h16)0,(h16)0,(h16)0};
      #pragma unroll
      for(int j=0;j<4;j++) if (c4+j==r){ h4[j]=ah; l4[j]=al_; }
      h4_st(Xh,r,c4,h4); h4_st(Xl,r,c4,l4);
    }
  }
  __syncthreads();
  f32x4 acc[2][2];
  for(int it=0;it<NS_IT;it++){
    mmA(Ah,Al,Xh,Xl,acc,lane,wv); __syncthreads();
    st_mm(Th,Tl,acc,lane,wv,-1.f,2.f); __syncthreads();   // T = 2I - A X
    mmA(Xh,Xl,Th,Tl,acc,lane,wv); __syncthreads();
    st_mm(Xh,Xl,acc,lane,wv,1.f,0.f); __syncthreads();    // X = X T
  }
}

__device__ __forceinline__ float cfj(int j, int J){
  return (j<=J)? 1.f/(float)(2*j+1) : 0.f;
}

// ---------------- logm (MFMA). A holds M + cshift*I on entry. --------------
// Returns accOut = P*R in f32 regs; caller: L = 2*accOut + ln(c)*I.
__device__ void logm2(h16* Ah,h16* Al, h16* Xh,h16* Xl, h16* Th,h16* Tl,
                      h16* Wh,h16* Wl, h16* parkh, float* red,
                      float cshift, int C, int J, int tid,int lane,int wv,
                      f32x4 accOut[2][2]){
  ns_inv2(Ah,Al,Xh,Xl,Th,Tl,red,tid,lane,wv,cshift);      // X = A^-1
  diag_add(Ah,Al,-2.f*cshift,tid);                        // A -> A - 2cI (exact)
  __syncthreads();
  f32x4 acc[2][2];
  mmA(Ah,Al,Xh,Xl,acc,lane,wv); __syncthreads();          // R = (A-2cI) X
  st_mm(Th,Tl,acc,lane,wv,1.f,0.f);
  st_park(parkh,acc,lane,wv);
  __syncthreads();
  mmA(Th,Tl,Th,Tl,acc,lane,wv); __syncthreads();          // S = R^2
  st_mm(Ah,Al,acc,lane,wv,1.f,0.f); __syncthreads();
  mmA(Ah,Al,Ah,Al,acc,lane,wv); __syncthreads();          // S2
  st_mm(Xh,Xl,acc,lane,wv,1.f,0.f); __syncthreads();
  mmA(Xh,Xl,Ah,Al,acc,lane,wv); __syncthreads();          // W = S2*S
  st_mm(Wh,Wl,acc,lane,wv,1.f,0.f); __syncthreads();
  {
    float a0=cfj(3*C-3,J), a1=cfj(3*C-2,J), a2=cfj(3*C-1,J);
    int r=tid>>2;
    #pragma unroll
    for(int q=0;q<4;q++){
      int c4=(tid&3)*16+q*4;
      h16x4 sh=h4_ld(Ah,r,c4), sl=h4_ld(Al,r,c4);
      h16x4 th=h4_ld(Xh,r,c4), tl=h4_ld(Xl,r,c4);
      h16x4 h4,l4;
      #pragma unroll
      for(int j=0;j<4;j++){
        float v = a1*join2(sh[j],sl[j]) + a2*join2(th[j],tl[j]);
        if (c4+j==r) v+=a0;
        h16 hh,ll; split2(v,hh,ll); h4[j]=hh; l4[j]=ll;
      }
      h4_st(Th,r,c4,h4); h4_st(Tl,r,c4,l4);               // P = q_{C-1}(S)
    }
  }
  __syncthreads();
  for(int i=C-2;i>=0;i--){                                // P = P*W + q_i(S)
    mmA(Th,Tl,Wh,Wl,acc,lane,wv);
    addq2(acc,Ah,Al,Xh,Xl,lane,wv,cfj(3*i,J),cfj(3*i+1,J),cfj(3*i+2,J));
    __syncthreads();
    st_mm(Th,Tl,acc,lane,wv,1.f,0.f);
    __syncthreads();
  }
  mmA_g(Th,Tl,parkh,accOut,lane,wv);                      // P * R (R from park)
}

// ---------------- exp(s*L) (MFMA). L preserved; result in P slot. ----------
__device__ void exp2_(h16* Lh,h16* Ll,h16* L2h,h16* L2l,h16* Wh,h16* Wl,
                      h16* Ph,h16* Pl, float s, int tid,int lane,int wv){
  f32x4 acc[2][2];
  mmA(Lh,Ll,Lh,Ll,acc,lane,wv); __syncthreads();
  st_mm(L2h,L2l,acc,lane,wv,1.f,0.f); __syncthreads();
  mmA(L2h,L2l,Lh,Ll,acc,lane,wv); __syncthreads();
  st_mm(Wh,Wl,acc,lane,wv,1.f,0.f); __syncthreads();
  float aj[15]; aj[0]=1.f;
  #pragma unroll
  for(int j=1;j<15;j++) aj[j]=aj[j-1]*s/(float)j;
  {
    int r=tid>>2;
    #pragma unroll
    for(int q=0;q<4;q++){
      int c4=(tid&3)*16+q*4;
      h16x4 sh=h4_ld(Lh,r,c4), sl=h4_ld(Ll,r,c4);
      h16x4 th=h4_ld(L2h,r,c4), tl=h4_ld(L2l,r,c4);
      h16x4 h4,l4;
      #pragma unroll
      for(int j=0;j<4;j++){
        float v = aj[13]*join2(sh[j],sl[j]) + aj[14]*join2(th[j],tl[j]);
        if (c4+j==r) v+=aj[12];
        h16 hh,ll; split2(v,hh,ll); h4[j]=hh; l4[j]=ll;
      }
      h4_st(Ph,r,c4,h4); h4_st(Pl,r,c4,l4);
    }
  }
  __syncthreads();
  #pragma unroll
  for(int i=3;i>=0;i--){
    mmA(Ph,Pl,Wh,Wl,acc,lane,wv);
    addq2(acc,Lh,Ll,L2h,L2l,lane,wv,aj[3*i],aj[3*i+1],aj[3*i+2]);
    __syncthreads();
    st_mm(Ph,Pl,acc,lane,wv,1.f,0.f);
    __syncthreads();
  }
}

// ---------------- coupled NS sqrt (MFMA): Y->(G)^{1/2}, Z->(G)^{-1/2} ------
__device__ void ns_sqrt2(h16* Yh,h16* Yl,h16* Zh,h16* Zl,h16* Th,h16* Tl,
                         int tid,int lane,int wv){
  {
    int r=tid>>2;
    h16 oh,ol; split2(1.f,oh,ol);
    #pragma unroll
    for(int q=0;q<4;q++){
      int c4=(tid&3)*16+q*4;
      h16x4 h4={(h16)0,(h16)0,(h16)0,(h16)0};
      h16x4 l4={(h16)0,(h16)0,(h16)0,(h16)0};
      #pragma unroll
      for(int j=0;j<4;j++) if (c4+j==r){ h4[j]=oh; l4[j]=ol; }
      h4_st(Zh,r,c4,h4); h4_st(Zl,r,c4,l4);
    }
  }
  __syncthreads();
  f32x4 aY[2][2], aZ[2][2];
  for(int it=0; it<NSC_IT; it++){
    mmA(Zh,Zl,Yh,Yl,aY,lane,wv); __syncthreads();
    st_mm(Th,Tl,aY,lane,wv,-0.5f,1.5f); __syncthreads();  // U = 1.5I - 0.5 Z Y
    mmA(Yh,Yl,Th,Tl,aY,lane,wv);                          // Y U
    mmA(Th,Tl,Zh,Zl,aZ,lane,wv);                          // U Z
    __syncthreads();
    st_mm(Yh,Yl,aY,lane,wv,1.f,0.f);
    st_mm(Zh,Zl,aZ,lane,wv,1.f,0.f);
    __syncthreads();
  }
}

// ---------------- kernels ----------------

// BiMap (f32 VALU) + logm(S1) via MFMA
__global__ __launch_bounds__(256) void kA(const float* __restrict__ Xg, const float* alphaP,
    const float* __restrict__ Wg, float* S1g, float* R2){
  __shared__ __align__(16) char lds[65536];
  int tid=threadIdx.x, tx=tid&15, ty=tid>>4, b=blockIdx.x;
  int lane=tid&63, wv=tid>>6;
  const float* Xb = Xg + (size_t)b*16384;
  float* Wl=(float*)lds;            // [128][64]
  float* Tl=(float*)(lds+32768);    // [128][64]
  #pragma unroll
  for(int i=0;i<8;i++){ int o=4*tid+i*1024; st4(Wl+o, ld4(Wg+o)); }
  float tv = (tid<128)? Xb[tid*129] : 0.f;
  float tr = block_sum(tv, Tl, tid);      // trace(X); also syncs W staging
  float al = alphaP[0];
  float f1 = 1.f/(tr+1e-4f);
  float scl = (1.f-al)*f1;
  float shift = al*(tr*f1)*(1.f/128.f);
  // T = X' W
  float a8[8][4];
  #pragma unroll
  for(int r=0;r<8;r++){ a8[r][0]=0;a8[r][1]=0;a8[r][2]=0;a8[r][3]=0; }
  for(int k=0;k<128;k++){
    float4 x0 = ld4(Xb + k*128 + 8*ty);
    float4 x1 = ld4(Xb + k*128 + 8*ty+4);
    float av[8] = {x0.x,x0.y,x0.z,x0.w,x1.x,x1.y,x1.z,x1.w};
    #pragma unroll
    for(int r=0;r<8;r++) av[r]*=scl;
    if ((k>>3)==ty) av[k&7] += shift;
    float4 bv = ld4(Wl + k*64 + 4*tx);
    const float* bf=(const float*)&bv;
    #pragma unroll
    for(int r=0;r<8;r++)
      #pragma unroll
      for(int c=0;c<4;c++) a8[r][c]=fmaf(av[r],bf[c],a8[r][c]);
  }
  __syncthreads();
  #pragma unroll
  for(int r=0;r<8;r++){
    float4 v; v.x=a8[r][0]; v.y=a8[r][1]; v.z=a8[r][2]; v.w=a8[r][3];
    st4(Tl + (8*ty+r)*64 + 4*tx, v);
  }
  __syncthreads();
  // S1 = W^T T
  float acc[4][4];
  #pragma unroll
  for(int r=0;r<4;r++){ acc[r][0]=0;acc[r][1]=0;acc[r][2]=0;acc[r][3]=0; }
  for(int k=0;k<128;k++){
    float4 a = ld4(Wl + k*64 + 4*ty);
    float4 bv= ld4(Tl + k*64 + 4*tx);
    const float* af=(const float*)&a; const float* bf=(const float*)&bv;
    #pragma unroll
    for(int r=0;r<4;r++)
      #pragma unroll
      for(int c=0;c<4;c++) acc[r][c]=fmaf(af[r],bf[c],acc[r][c]);
  }
  __syncthreads();
  st64(S1g + (size_t)b*4096, acc, tx,ty, 1.f,0.f);
  // A-planes = (S1 + C1*I)^T  (split-f16, swizzled)
  h16* s0h=(h16*)lds;          h16* s0l=s0h+4096;
  h16* s1h=(h16*)(lds+16384);  h16* s1l=s1h+4096;
  h16* s2h=(h16*)(lds+32768);  h16* s2l=s2h+4096;
  h16* s3h=(h16*)(lds+49152);  h16* s3l=s3h+4096;
  #pragma unroll
  for(int c=0;c<4;c++){
    int j=4*tx+c;
    h16x4 h4,l4;
    #pragma unroll
    for(int r=0;r<4;r++){
      float x=acc[r][c];
      if (4*ty+r==j) x+=C1;
      h16 hh,ll; split2(x,hh,ll); h4[r]=hh; l4[r]=ll;
    }
    int off=(j*128+(4*ty)*2)^((j&7)<<4);
    *(h16x4*)((char*)s0h+off)=h4;
    *(h16x4*)((char*)s0l+off)=l4;
  }
  __syncthreads();
  f32x4 aL[2][2];
  h16* parkh=(h16*)(R2+(size_t)b*4096);
  logm2(s0h,s0l,s1h,s1l,s2h,s2l,s3h,s3l,parkh,(float*)s3h,
        C1, 11, 30, tid,lane,wv, aL);
  __syncthreads();
  st_gl(R2+(size_t)b*4096, aL, lane,wv, 2.f, LNC1);       // L1 = 2 P R + ln(c) I
}

// column-mean over batch (unchanged)
__global__ __launch_bounds__(256) void kRed(const float* __restrict__ R2, float* outM, float scale){
  __shared__ float red[256];
  int tid=threadIdx.x; int ee=tid&31; int sl=tid>>5;
  int e0 = blockIdx.x*32 + ee;
  float s=0.f;
  for(int j=0;j<256;j++) s += R2[(size_t)(sl+8*j)*4096 + e0];
  red[tid]=s; __syncthreads();
  if (sl<4) red[tid]+=red[tid+128];
  __syncthreads();
  if (sl<2) red[tid]+=red[tid+64];
  __syncthreads();
  if (sl==0) outM[e0] = (red[tid]+red[tid+32])*scale;
}

// G0^{+-1/2} = exp(+-Lbar/2); Bs = sqrt(sym(bn_bias)) via coupled NS
__global__ __launch_bounds__(256) void kB(const float* Lbar, const float* biasP,
     float* Gi0, float* Gs0, float* Bs){
  __shared__ __align__(16) char lds[65536];
  int tid=threadIdx.x, lane=tid&63, wv=tid>>6;
  h16* s0h=(h16*)lds;          h16* s0l=s0h+4096;
  h16* s1h=(h16*)(lds+16384);  h16* s1l=s1h+4096;
  h16* s2h=(h16*)(lds+32768);  h16* s2l=s2h+4096;
  h16* s3h=(h16*)(lds+49152);  h16* s3l=s3h+4096;
  float tr = block_sum((tid<64)? Lbar[tid*65]:0.f, (float*)s3h, tid);
  float cb_ = tr*(1.f/64.f);
  fill_gl(s0h,s0l, Lbar, 0.5f, -cb_, tid);                // D/2
  __syncthreads();
  exp2_(s0h,s0l,s1h,s1l,s2h,s2l,s3h,s3l, 1.f, tid,lane,wv);
  float eg = expf(0.5f*cb_);
  plane_out(s3h,s3l, Gs0, eg, tid);
  __syncthreads();
  exp2_(s0h,s0l,s1h,s1l,s2h,s2l,s3h,s3l, -1.f, tid,lane,wv);
  float egi = expf(-0.5f*cb_);
  plane_out(s3h,s3l, Gi0, egi, tid);
  __syncthreads();
  float tb = block_sum((tid<64)? biasP[tid*65]:0.f, (float*)s2h, tid);
  float itb=1.f/tb;
  { // Y = sym(bias)/tb
    int r=tid>>2;
    #pragma unroll
    for(int q=0;q<4;q++){
      int c4=(tid&3)*16+q*4;
      float4 v=ld4(biasP + r*64 + c4);
      float vv[4]={v.x,v.y,v.z,v.w};
      h16x4 h4,l4;
      #pragma unroll
      for(int j=0;j<4;j++){
        float x = 0.5f*(vv[j] + biasP[(c4+j)*64 + r]) * itb;
        h16 hh,ll; split2(x,hh,ll); h4[j]=hh; l4[j]=ll;
      }
      h4_st(s0h,r,c4,h4); h4_st(s0l,r,c4,l4);
    }
  }
  __syncthreads();
  ns_sqrt2(s0h,s0l,s1h,s1l,s2h,s2l,tid,lane,wv);
  float stb=sqrtf(tb);
  plane_out(s0h,s0l, Bs, stb, tid);
}

// Karcher-step log: M = Gi S1 Gi ; L = logm(M) -> R2 ; optional v accumulation
__global__ __launch_bounds__(256) void kC(const float* __restrict__ S1g, const float* GiP,
     float* R2, float* vpart, int doV){
  __shared__ __align__(16) char lds[65536];
  int tid=threadIdx.x, b=blockIdx.x, lane=tid&63, wv=tid>>6;
  h16* s0h=(h16*)lds;          h16* s0l=s0h+4096;
  h16* s1h=(h16*)(lds+16384);  h16* s1l=s1h+4096;
  h16* s2h=(h16*)(lds+32768);  h16* s2l=s2h+4096;
  h16* s3h=(h16*)(lds+49152);  h16* s3l=s3h+4096;
  fill_gl(s0h,s0l, S1g+(size_t)b*4096, 1.f,0.f, tid);
  fill_gl(s1h,s1l, GiP, 1.f,0.f, tid);
  __syncthreads();
  f32x4 acc[2][2];
  mmA(s0h,s0l,s1h,s1l,acc,lane,wv); __syncthreads();      // S1 Gi
  st_mm(s2h,s2l,acc,lane,wv,1.f,0.f); __syncthreads();
  mmA(s1h,s1l,s2h,s2l,acc,lane,wv); __syncthreads();      // M = Gi S1 Gi
  st_mm(s0h,s0l,acc,lane,wv,1.f,1.f); __syncthreads();    // A = M + I
  f32x4 aL[2][2];
  h16* parkh=(h16*)(R2+(size_t)b*4096);
  logm2(s0h,s0l,s1h,s1l,s2h,s2l,s3h,s3l,parkh,(float*)s3h,
        1.f, 11, 30, tid,lane,wv, aL);
  __syncthreads();
  st_gl(R2+(size_t)b*4096, aL, lane,wv, 2.f, 0.f);
  if (doV){
    float s=0.f;
    #pragma unroll
    for(int rt=0;rt<2;rt++)
      #pragma unroll
      for(int ct=0;ct<2;ct++)
        #pragma unroll
        for(int r=0;r<4;r++){ float lv=2.f*aL[rt][ct][r]; s=fmaf(lv,lv,s); }
    __syncthreads();
    s = block_sum(s, (float*)s3h, tid);
    if (tid==0) atomicAdd(vpart + (b&31), s);
  }
}

// G_new = Gs exp(Ebar) Gs ; then G_new^{+-1/2} via coupled NS
__global__ __launch_bounds__(256) void kD(const float* Ebar, const float* GsP,
     float* GsN, float* GiN){
  __shared__ __align__(16) char lds[65536];
  int tid=threadIdx.x, lane=tid&63, wv=tid>>6;
  h16* s0h=(h16*)lds;          h16* s0l=s0h+4096;
  h16* s1h=(h16*)(lds+16384);  h16* s1l=s1h+4096;
  h16* s2h=(h16*)(lds+32768);  h16* s2l=s2h+4096;
  h16* s3h=(h16*)(lds+49152);  h16* s3l=s3h+4096;
  fill_gl(s0h,s0l, Ebar, 1.f,0.f, tid); __syncthreads();
  exp2_(s0h,s0l,s1h,s1l,s2h,s2l,s3h,s3l, 1.f, tid,lane,wv);  // E in s3
  fill_gl(s0h,s0l, GsP, 1.f,0.f, tid);
  __syncthreads();
  f32x4 acc[2][2];
  mmA(s3h,s3l,s0h,s0l,acc,lane,wv); __syncthreads();      // E Gs
  st_mm(s1h,s1l,acc,lane,wv,1.f,0.f); __syncthreads();
  mmA(s0h,s0l,s1h,s1l,acc,lane,wv);                       // G = Gs (E Gs)
  float tv=0.f;
  {
    int lr=lane&15, lq=lane>>4, rb=(wv&1)*32, cb=(wv>>1)*32;
    #pragma unroll
    for(int rt=0;rt<2;rt++)
      #pragma unroll
      for(int ct=0;ct<2;ct++)
        #pragma unroll
        for(int r=0;r<4;r++)
          if (rb+16*rt+lq*4+r == cb+16*ct+lr) tv+=acc[rt][ct][r];
  }
  __syncthreads();
  float t = block_sum(tv, (float*)s2h, tid);
  st_mm(s0h,s0l,acc,lane,wv,1.f/t,0.f); __syncthreads();
  ns_sqrt2(s0h,s0l,s1h,s1l,s2h,s2l,tid,lane,wv);
  float st_=sqrtf(t), ist=1.f/st_;
  plane_out(s0h,s0l, GsN, st_, tid);
  plane_out(s1h,s1l, GiN, ist, tid);
}

__global__ void kF2(const float* vpart, const float* gammaP, float* sOut){
  if (threadIdx.x==0 && blockIdx.x==0){
    float v=0.f;
    for(int i=0;i<32;i++) v+=vpart[i];
    v *= (1.f/2048.f);
    sOut[0] = gammaP[0] / sqrtf(v + 1e-5f);
  }
}

// Y=exp(s Lt); Z=Bs Y Bs; Lg=logm(Z); out = triu(Lg)*coef @ Wc^T + bc
__global__ __launch_bounds__(256) void kG(float* R2, const float* BsP, const float* sP,
     const float* __restrict__ WcP, const float* bcP, float* outP){
  __shared__ __align__(16) char lds[65536];
  int tid=threadIdx.x, b=blockIdx.x, lane=tid&63, wv=tid>>6;
  h16* s0h=(h16*)lds;          h16* s0l=s0h+4096;
  h16* s1h=(h16*)(lds+16384);  h16* s1l=s1h+4096;
  h16* s2h=(h16*)(lds+32768);  h16* s2l=s2h+4096;
  h16* s3h=(h16*)(lds+49152);  h16* s3l=s3h+4096;
  fill_gl(s0h,s0l, R2+(size_t)b*4096, 1.f,0.f, tid); __syncthreads();  // Lt
  float s = sP[0];
  exp2_(s0h,s0l,s1h,s1l,s2h,s2l,s3h,s3l, s, tid,lane,wv); // Y in s3
  fill_gl(s0h,s0l, BsP, 1.f,0.f, tid);
  __syncthreads();
  f32x4 acc[2][2];
  mmA(s3h,s3l,s0h,s0l,acc,lane,wv); __syncthreads();      // Y Bs
  st_mm(s1h,s1l,acc,lane,wv,1.f,0.f); __syncthreads();
  mmA(s0h,s0l,s1h,s1l,acc,lane,wv); __syncthreads();      // Z = Bs Y Bs
  st_mm(s2h,s2l,acc,lane,wv,1.f,1.f); __syncthreads();    // A = Z + I
  f32x4 aL[2][2];
  h16* parkh=(h16*)(R2+(size_t)b*4096);
  logm2(s2h,s2l,s0h,s0l,s1h,s1l,s3h,s3l,parkh,(float*)s3h,
        1.f, 6, 15, tid,lane,wv, aL);
  // epilogue: triu(2*P*R) * coef @ Wc^T
  float o0=0,o1=0,o2=0,o3=0;
  {
    int lr=lane&15, lq=lane>>4, rb=(wv&1)*32, cb=(wv>>1)*32;
    #pragma unroll
    for(int rt=0;rt<2;rt++)
      #pragma unroll
      for(int ct=0;ct<2;ct++)
        #pragma unroll
        for(int r=0;r<4;r++){
          int i=rb+16*rt+lq*4+r, j=cb+16*ct+lr;
          float lg2=2.f*aL[rt][ct][r];
          int a=(i<j)? i:j, bb=(i<j)? j:i;
          int tri = a*64 - ((a*(a-1))>>1) + (bb-a);
          float w = (i==j)? lg2 : lg2*0.70710678118654752f;
          o0=fmaf(w, WcP[tri],      o0);
          o1=fmaf(w, WcP[2080+tri], o1);
          o2=fmaf(w, WcP[4160+tri], o2);
          o3=fmaf(w, WcP[6240+tri], o3);
        }
  }
  __syncthreads();
  float* redv=(float*)lds;
  float4 pk; pk.x=o0; pk.y=o1; pk.z=o2; pk.w=o3;
  st4(redv+4*tid, pk); __syncthreads();
  for(int off=128; off>0; off>>=1){
    if (tid<off){
      float4 x=ld4(redv+4*tid), y=ld4(redv+4*(tid+off));
      x.x+=y.x; x.y+=y.y; x.z+=y.z; x.w+=y.w;
      st4(redv+4*tid, x);
    }
    __syncthreads();
  }
  if (tid==0){
    outP[b*4+0]=redv[0]+bcP[0];
    outP[b*4+1]=redv[1]+bcP[1];
    outP[b*4+2]=redv[2]+bcP[2];
    outP[b*4+3]=redv[3]+bcP[3];
  }
}

extern "C" void kernel_launch(void* const* d_in, const int* in_sizes, int n_in,
                              void* d_out, int out_size, void* d_ws, size_t ws_size,
                              hipStream_t stream){
  const float* X     = (const float*)d_in[0];
  const float* alpha = (const float*)d_in[1];
  const float* W     = (const float*)d_in[2];
  const float* gamma = (const float*)d_in[3];
  const float* bias  = (const float*)d_in[4];
  const float* Wc    = (const float*)d_in[5];
  const float* bc    = (const float*)d_in[6];
  float* ws = (float*)d_ws;
  float* S1 = ws + WS_S1;
  float* R2 = ws + WS_R2;
  float* sm = ws + WS_SM;

  hipMemsetAsync(sm + SM_VPART, 0, 33*sizeof(float), stream);

  kA  <<<2048,256,0,stream>>>(X, alpha, W, S1, R2);
  kRed<<<128, 256,0,stream>>>(R2, sm+SM_LBAR, 1.f/2048.f);
  kB  <<<1,   256,0,stream>>>(sm+SM_LBAR, bias, sm+SM_GI0, sm+SM_GS0, sm+SM_BS);
  kC  <<<2048,256,0,stream>>>(S1, sm+SM_GI0, R2, nullptr, 0);
  kRed<<<128, 256,0,stream>>>(R2, sm+SM_EBAR1, 1.f/2048.f);
  kD  <<<1,   256,0,stream>>>(sm+SM_EBAR1, sm+SM_GS0, sm+SM_GS1, sm+SM_GI1);
  kC  <<<2048,256,0,stream>>>(S1, sm+SM_GI1, R2, nullptr, 0);
  kRed<<<128, 256,0,stream>>>(R2, sm+SM_EBAR2, 1.f/2048.f);
  kD  <<<1,   256,0,stream>>>(sm+SM_EBAR2, sm+SM_GS1, sm+SM_GS2, sm+SM_GI2);
  kC  <<<2048,256,0,stream>>>(S1, sm+SM_GI2, R2, sm+SM_VPART, 1);
  kF2 <<<1,1,0,stream>>>(sm+SM_VPART, gamma, sm+SM_S);
  kG  <<<2048,256,0,stream>>>(R2, sm+SM_BS, sm+SM_S, Wc, bc, (float*)d_out);
}

// Round 3
// 923.148 us; speedup vs baseline: 4.5915x; 1.5673x over previous
//
#include <hip/hip_runtime.h>
#include <math.h>

// ============================================================================
// SPDNet forward, eig-free — v3b (v3 with kA LDS capped back to 64 KB):
//  * BiMap (W^T X W) via split-f16 MFMA (was f32 VALU)
//  * Newton-Schulz inverse: 5 hi-only iters (self-correcting) + 2 split iters
//  * poly q(S) contributions register-cached (no per-iter LDS re-reads)
//  * diag masks precomputed (dI regs, 1 fma instead of cmp+sel)
//  * logm/exp restructured to 3 LDS slots (48KB) -> kC/kG 3 blocks/CU
// Split scheme: v = hi + lo/4096 (f16,f16), 3 MFMAs = fp32-class accuracy.
// Planes store TRANSPOSE of semantic matrix; mm(L,R) = L^T R (left ops symm).
// ============================================================================

#define NS_HI   5
#define NSC_IT  12
#define C1      0.0038729833f
#define LNC1    (-5.553730f)
#define SPLIT_S 4096.f
#define SPLIT_R (1.f/4096.f)

typedef _Float16 h16;
typedef _Float16 h16x8 __attribute__((ext_vector_type(8)));
typedef _Float16 h16x4 __attribute__((ext_vector_type(4)));
typedef float    f32x4 __attribute__((ext_vector_type(4)));

// ws layout (floats)
#define WS_S1   ((size_t)0)
#define WS_R2   ((size_t)8388608)
#define WS_SM   ((size_t)16777216)
#define SM_LBAR  0
#define SM_EBAR1 4096
#define SM_EBAR2 8192
#define SM_GI0   12288
#define SM_GS0   16384
#define SM_GI1   20480
#define SM_GS1   24576
#define SM_GI2   28672
#define SM_GS2   32768
#define SM_BS    36864
#define SM_VPART 40960
#define SM_S     40992

__device__ __forceinline__ float4 ld4(const float* p){ return *(const float4*)p; }
__device__ __forceinline__ void  st4(float* p, float4 v){ *(float4*)p = v; }

// ---------------- split-f16 plane helpers (64x64, 128B row stride) ---------
__device__ __forceinline__ int eoff(int r, int c){ return (r*128 + c*2) ^ ((r&7)<<4); }

__device__ __forceinline__ h16x8 frag_ld(const h16* p, int row, int ks, int lg){
  int off = (row*128 + ks*64 + lg*16) ^ ((row&7)<<4);
  return *(const h16x8*)((const char*)p + off);
}
// 64x128 plane (256B row stride), ks in 0..3
__device__ __forceinline__ h16x8 frag_ld2(const h16* p, int row, int ks, int lg){
  int off = (row*256 + ks*64 + lg*16) ^ ((row&7)<<4);
  return *(const h16x8*)((const char*)p + off);
}
__device__ __forceinline__ h16x4 h4_ld(const h16* p, int r, int c4){
  return *(const h16x4*)((const char*)p + eoff(r,c4));
}
__device__ __forceinline__ void h4_st(h16* p, int r, int c4, h16x4 v){
  *(h16x4*)((char*)p + eoff(r,c4)) = v;
}
__device__ __forceinline__ void split2(float v, h16& h, h16& l){
  h16 hh = (h16)v;
  h = hh;
  l = (h16)((v - (float)hh) * SPLIT_S);
}
__device__ __forceinline__ float join2(h16 h, h16 l){
  return (float)h + (float)l * SPLIT_R;
}

// ---------------- MFMA 64x64x64: D = L^T * R ------------------------------
// AS/BS: whether left/right lo-planes participate. GP: B from global (linear).
template<int AS,int BS,int GP>
__device__ __forceinline__ void mmT(const h16* Lh,const h16* Ll,
                                    const h16* Rh,const h16* Rl,const h16* gR,
                                    f32x4 acc[2][2], int lane,int wv){
  const int lr=lane&15, lg=lane>>4;
  const int rb=(wv&1)*32, cb=(wv>>1)*32;
  h16x8 ah[2][2], al[2][2];
  #pragma unroll
  for(int rt=0;rt<2;rt++){
    #pragma unroll
    for(int ks=0;ks<2;ks++){
      ah[rt][ks]=frag_ld(Lh, rb+16*rt+lr, ks, lg);
      if(AS) al[rt][ks]=frag_ld(Ll, rb+16*rt+lr, ks, lg);
    }
  }
  f32x4 aM[2][2], aC[2][2];
  const f32x4 vz={0.f,0.f,0.f,0.f};
  #pragma unroll
  for(int rt=0;rt<2;rt++){ aM[rt][0]=vz; aM[rt][1]=vz; aC[rt][0]=vz; aC[rt][1]=vz; }
  #pragma unroll
  for(int ct=0;ct<2;ct++){
    #pragma unroll
    for(int ks=0;ks<2;ks++){
      h16x8 bh, bl;
      if(GP){
        const h16* g = gR + (cb+16*ct+lr)*64 + ks*32 + lg*8;
        bh = *(const h16x8*)g;
        if(BS) bl = *(const h16x8*)(g+4096);
      }else{
        bh = frag_ld(Rh, cb+16*ct+lr, ks, lg);
        if(BS) bl = frag_ld(Rl, cb+16*ct+lr, ks, lg);
      }
      #pragma unroll
      for(int rt=0;rt<2;rt++){
        aM[rt][ct]=__builtin_amdgcn_mfma_f32_16x16x32_f16(ah[rt][ks],bh,aM[rt][ct],0,0,0);
        if(AS) aC[rt][ct]=__builtin_amdgcn_mfma_f32_16x16x32_f16(al[rt][ks],bh,aC[rt][ct],0,0,0);
        if(BS) aC[rt][ct]=__builtin_amdgcn_mfma_f32_16x16x32_f16(ah[rt][ks],bl,aC[rt][ct],0,0,0);
      }
    }
  }
  #pragma unroll
  for(int rt=0;rt<2;rt++)
    #pragma unroll
    for(int ct=0;ct<2;ct++)
      acc[rt][ct] = (AS||BS) ? (aM[rt][ct] + aC[rt][ct]*SPLIT_R) : aM[rt][ct];
}

// split store to plane (transposed): x = acc*scale + dadd*dI
__device__ __forceinline__ void stS(h16* Dh,h16* Dl,const f32x4 acc[2][2],
                                    const float (*dI)[2][4],
                                    int lane,int wv,float scale,float dadd){
  const int lr=lane&15, lg=lane>>4, rb=(wv&1)*32, cb=(wv>>1)*32;
  #pragma unroll
  for(int rt=0;rt<2;rt++){
    int i0=rb+16*rt+lg*4;
    #pragma unroll
    for(int ct=0;ct<2;ct++){
      int j=cb+16*ct+lr;
      h16x4 h4,l4;
      #pragma unroll
      for(int r=0;r<4;r++){
        float x=fmaf(acc[rt][ct][r],scale, dadd*dI[rt][ct][r]);
        h16 hh,ll; split2(x,hh,ll); h4[r]=hh; l4[r]=ll;
      }
      int off=(j*128+i0*2)^((j&7)<<4);
      *(h16x4*)((char*)Dh+off)=h4;
      *(h16x4*)((char*)Dl+off)=l4;
    }
  }
}
// hi-only store
__device__ __forceinline__ void stH(h16* Dh,const f32x4 acc[2][2],
                                    const float (*dI)[2][4],
                                    int lane,int wv,float scale,float dadd){
  const int lr=lane&15, lg=lane>>4, rb=(wv&1)*32, cb=(wv>>1)*32;
  #pragma unroll
  for(int rt=0;rt<2;rt++){
    int i0=rb+16*rt+lg*4;
    #pragma unroll
    for(int ct=0;ct<2;ct++){
      int j=cb+16*ct+lr;
      h16x4 h4;
      #pragma unroll
      for(int r=0;r<4;r++){
        float x=fmaf(acc[rt][ct][r],scale, dadd*dI[rt][ct][r]);
        h4[r]=(h16)x;
      }
      int off=(j*128+i0*2)^((j&7)<<4);
      *(h16x4*)((char*)Dh+off)=h4;
    }
  }
}

// store D to global f32 (outputs symmetric; transpose ok)
__device__ __forceinline__ void st_gl(float* G, const f32x4 acc[2][2],
                                      int lane,int wv,float scale,float dadd){
  const int lr=lane&15, lg=lane>>4, rb=(wv&1)*32, cb=(wv>>1)*32;
  #pragma unroll
  for(int rt=0;rt<2;rt++){
    int i0=rb+16*rt+lg*4;
    #pragma unroll
    for(int ct=0;ct<2;ct++){
      int j=cb+16*ct+lr;
      float4 v; float* vf=(float*)&v;
      #pragma unroll
      for(int r=0;r<4;r++){
        float x=acc[rt][ct][r]*scale;
        if (i0+r==j) x += dadd;
        vf[r]=x;
      }
      st4(G + j*64 + i0, v);
    }
  }
}

// park D to global split (hi at gh[0:4096], lo at gh[4096:8192]), linear
__device__ __forceinline__ void st_park(h16* gh, const f32x4 acc[2][2], int lane,int wv){
  const int lr=lane&15, lg=lane>>4, rb=(wv&1)*32, cb=(wv>>1)*32;
  #pragma unroll
  for(int rt=0;rt<2;rt++){
    int i0=rb+16*rt+lg*4;
    #pragma unroll
    for(int ct=0;ct<2;ct++){
      int j=cb+16*ct+lr;
      h16x4 h4,l4;
      #pragma unroll
      for(int r=0;r<4;r++){ h16 hh,ll; split2(acc[rt][ct][r],hh,ll); h4[r]=hh; l4[r]=ll; }
      *(h16x4*)(gh + j*64 + i0) = h4;
      *(h16x4*)(gh + 4096 + j*64 + i0) = l4;
    }
  }
}

// snapshot plane values at this thread's D positions into registers
__device__ __forceinline__ void snap(const h16* Ph,const h16* Pl,float (*v)[2][4],
                                     int lane,int wv){
  const int lr=lane&15, lg=lane>>4, rb=(wv&1)*32, cb=(wv>>1)*32;
  #pragma unroll
  for(int rt=0;rt<2;rt++){
    int i0=rb+16*rt+lg*4;
    #pragma unroll
    for(int ct=0;ct<2;ct++){
      int j=cb+16*ct+lr;
      h16x4 h=h4_ld(Ph,j,i0), l=h4_ld(Pl,j,i0);
      #pragma unroll
      for(int r=0;r<4;r++) v[rt][ct][r]=join2(h[r],l[r]);
    }
  }
}

// fill planes from global f32 symmetric: x = (v + dshift_on_diag)*scale
__device__ __forceinline__ void fill_gl(h16* Ph, h16* Pl, const float* g,
                                        float scale, float dshift, int tid){
  int r = tid>>2;
  #pragma unroll
  for(int q=0;q<4;q++){
    int c4 = (tid&3)*16 + q*4;
    float4 v = ld4(g + r*64 + c4);
    float vv[4]={v.x,v.y,v.z,v.w};
    h16x4 h4,l4;
    #pragma unroll
    for(int j=0;j<4;j++){
      float x = vv[j];
      if (c4+j == r) x += dshift;
      x *= scale;
      h16 hh,ll; split2(x,hh,ll); h4[j]=hh; l4[j]=ll;
    }
    h4_st(Ph,r,c4,h4); h4_st(Pl,r,c4,l4);
  }
}

__device__ __forceinline__ void plane_out(const h16* Ph, const h16* Pl, float* g,
                                          float scale, int tid){
  int r=tid>>2;
  #pragma unroll
  for(int q=0;q<4;q++){
    int c4=(tid&3)*16+q*4;
    h16x4 h4=h4_ld(Ph,r,c4), l4=h4_ld(Pl,r,c4);
    float4 v;
    v.x=join2(h4[0],l4[0])*scale;
    v.y=join2(h4[1],l4[1])*scale;
    v.z=join2(h4[2],l4[2])*scale;
    v.w=join2(h4[3],l4[3])*scale;
    st4(g + r*64 + c4, v);
  }
}

__device__ __forceinline__ void diag_add(h16* Ph, h16* Pl, float add, int tid){
  if (tid<64){
    int off = (tid*128 + tid*2) ^ ((tid&7)<<4);
    h16* ph = (h16*)((char*)Ph + off);
    h16* pl = (h16*)((char*)Pl + off);
    float v = join2(*ph,*pl) + add;
    h16 hh,ll; split2(v,hh,ll);
    *ph=hh; *pl=ll;
  }
}

__device__ float block_sum(float v, float* red, int tid){
  red[tid]=v; __syncthreads();
  for(int off=128; off>0; off>>=1){
    if (tid<off) red[tid]+=red[tid+off];
    __syncthreads();
  }
  float r=red[0]; __syncthreads();
  return r;
}

__device__ __forceinline__ float cfj(int j, int J){
  return (j<=J)? 1.f/(float)(2*j+1) : 0.f;
}

// ---------------- Newton-Schulz inverse: 5 hi-only + 2 split iters --------
__device__ void ns_inv3(h16* Ah,h16* Al,h16* Xh,h16* Xl,h16* Th,h16* Tl,
                        float* red,const float (*dI)[2][4],
                        int tid,int lane,int wv,float lminB){
  {
    int row=tid>>2, seg=tid&3;
    float s=0.f;
    #pragma unroll
    for(int q=0;q<4;q++){
      h16x4 h4 = h4_ld(Ah,row,seg*16+q*4);
      #pragma unroll
      for(int j=0;j<4;j++) s += fabsf((float)h4[j]);
    }
    red[tid]=s*1.001f; __syncthreads();
    if((tid&3)==0) red[tid]=red[tid]+red[tid+1]+red[tid+2]+red[tid+3];
    __syncthreads();
    if(tid==0){ float m=0.f; for(int i=0;i<64;i++) m=fmaxf(m,red[4*i]); red[0]=m; }
    __syncthreads();
  }
  float alpha = 2.f/(lminB + red[0]);
  {
    int r=tid>>2;
    h16 ahh,all_; split2(alpha,ahh,all_);
    #pragma unroll
    for(int q=0;q<4;q++){
      int c4=(tid&3)*16+q*4;
      h16x4 h4={(h16)0,(h16)0,(h16)0,(h16)0};
      h16x4 l4={(h16)0,(h16)0,(h16)0,(h16)0};
      #pragma unroll
      for(int j=0;j<4;j++) if (c4+j==r){ h4[j]=ahh; l4[j]=all_; }
      h4_st(Xh,r,c4,h4); h4_st(Xl,r,c4,l4);
    }
  }
  __syncthreads();
  f32x4 acc[2][2];
  for(int it=0;it<NS_HI;it++){
    mmT<0,0,0>(Ah,0,Xh,0,0,acc,lane,wv); __syncthreads();
    stH(Th,acc,dI,lane,wv,-1.f,2.f); __syncthreads();      // T = 2I - A X (hi)
    mmT<0,0,0>(Xh,0,Th,0,0,acc,lane,wv); __syncthreads();
    stH(Xh,acc,dI,lane,wv,1.f,0.f); __syncthreads();       // X = X T (hi)
  }
  // promote: A split x X hi -> T split; X hi x T split -> X split
  mmT<1,0,0>(Ah,Al,Xh,0,0,acc,lane,wv); __syncthreads();
  stS(Th,Tl,acc,dI,lane,wv,-1.f,2.f); __syncthreads();
  mmT<0,1,0>(Xh,0,Th,Tl,0,acc,lane,wv); __syncthreads();
  stS(Xh,Xl,acc,dI,lane,wv,1.f,0.f); __syncthreads();
  // final full-split iter
  mmT<1,1,0>(Ah,Al,Xh,Xl,0,acc,lane,wv); __syncthreads();
  stS(Th,Tl,acc,dI,lane,wv,-1.f,2.f); __syncthreads();
  mmT<1,1,0>(Xh,Xl,Th,Tl,0,acc,lane,wv); __syncthreads();
  stS(Xh,Xl,acc,dI,lane,wv,1.f,0.f); __syncthreads();
}

// ---------------- logm, 3-slot. A holds M + cshift*I on entry. ------------
// accOut = P*R ; caller: L = 2*accOut + ln(c)*I.
__device__ void logm3(h16* Ah,h16* Al,h16* Xh,h16* Xl,h16* Th,h16* Tl,
                      h16* parkh, float* red, const float (*dI)[2][4],
                      float cshift,int C,int J,int tid,int lane,int wv,
                      f32x4 accOut[2][2]){
  ns_inv3(Ah,Al,Xh,Xl,Th,Tl,red,dI,tid,lane,wv,cshift);   // X = A^-1
  diag_add(Ah,Al,-2.f*cshift,tid);                        // A -> A - 2cI
  __syncthreads();
  f32x4 acc[2][2];
  mmT<1,1,0>(Ah,Al,Xh,Xl,0,acc,lane,wv); __syncthreads(); // R = (A-2cI) X
  stS(Th,Tl,acc,dI,lane,wv,1.f,0.f);
  st_park(parkh,acc,lane,wv);
  __syncthreads();
  mmT<1,1,0>(Th,Tl,Th,Tl,0,acc,lane,wv); __syncthreads(); // S = R^2
  stS(Ah,Al,acc,dI,lane,wv,1.f,0.f); __syncthreads();     // S -> A slot
  mmT<1,1,0>(Ah,Al,Ah,Al,0,acc,lane,wv); __syncthreads(); // S2
  stS(Xh,Xl,acc,dI,lane,wv,1.f,0.f); __syncthreads();     // S2 -> X slot
  float sv[2][2][4], s2v[2][2][4];
  f32x4 accw[2][2];
  mmT<1,1,0>(Xh,Xl,Ah,Al,0,accw,lane,wv);                 // W = S2 S = S^3
  snap(Ah,Al,sv,lane,wv);
  snap(Xh,Xl,s2v,lane,wv);
  { // P = q_{C-1}(S) elementwise -> T slot
    float a0=cfj(3*C-3,J),a1=cfj(3*C-2,J),a2=cfj(3*C-1,J);
    int r=tid>>2;
    #pragma unroll
    for(int q=0;q<4;q++){
      int c4=(tid&3)*16+q*4;
      h16x4 sh=h4_ld(Ah,r,c4), sl=h4_ld(Al,r,c4);
      h16x4 th=h4_ld(Xh,r,c4), tl=h4_ld(Xl,r,c4);
      h16x4 h4,l4;
      #pragma unroll
      for(int jj=0;jj<4;jj++){
        float v=a1*join2(sh[jj],sl[jj])+a2*join2(th[jj],tl[jj]);
        if(c4+jj==r) v+=a0;
        h16 hh,ll; split2(v,hh,ll); h4[jj]=hh; l4[jj]=ll;
      }
      h4_st(Th,r,c4,h4); h4_st(Tl,r,c4,l4);
    }
  }
  __syncthreads();
  stS(Xh,Xl,accw,dI,lane,wv,1.f,0.f); __syncthreads();    // W -> X slot
  for(int i=C-2;i>=0;i--){                                // P = P*W + q_i(S)
    mmT<1,1,0>(Th,Tl,Xh,Xl,0,acc,lane,wv);
    float a0=cfj(3*i,J),a1=cfj(3*i+1,J),a2=cfj(3*i+2,J);
    #pragma unroll
    for(int rt=0;rt<2;rt++)
      #pragma unroll
      for(int ct=0;ct<2;ct++)
        #pragma unroll
        for(int r=0;r<4;r++)
          acc[rt][ct][r]+=a0*dI[rt][ct][r]+a1*sv[rt][ct][r]+a2*s2v[rt][ct][r];
    __syncthreads();
    stS(Th,Tl,acc,dI,lane,wv,1.f,0.f);
    __syncthreads();
  }
  mmT<1,1,1>(Th,Tl,(const h16*)0,(const h16*)0,parkh,accOut,lane,wv); // P R
}

// ---------------- exp(s*L), 3-slot (L in slot A preserved; result in C) ----
__device__ void exp3(h16* Lh,h16* Ll, h16* Bh,h16* Bl, h16* Ph,h16* Pl,
                     const float (*dI)[2][4], float s,
                     int tid,int lane,int wv){
  f32x4 acc[2][2];
  mmT<1,1,0>(Lh,Ll,Lh,Ll,0,acc,lane,wv); __syncthreads();
  stS(Bh,Bl,acc,dI,lane,wv,1.f,0.f); __syncthreads();     // B = L2
  float lv[2][2][4], l2v[2][2][4];
  snap(Lh,Ll,lv,lane,wv);
  snap(Bh,Bl,l2v,lane,wv);
  float aj[15]; aj[0]=1.f;
  #pragma unroll
  for(int j=1;j<15;j++) aj[j]=aj[j-1]*s/(float)j;
  { // P init elementwise from L, L2 planes -> P slot
    int r=tid>>2;
    #pragma unroll
    for(int q=0;q<4;q++){
      int c4=(tid&3)*16+q*4;
      h16x4 sh=h4_ld(Lh,r,c4), sl=h4_ld(Ll,r,c4);
      h16x4 th=h4_ld(Bh,r,c4), tl=h4_ld(Bl,r,c4);
      h16x4 h4,l4;
      #pragma unroll
      for(int jj=0;jj<4;jj++){
        float v = aj[13]*join2(sh[jj],sl[jj]) + aj[14]*join2(th[jj],tl[jj]);
        if (c4+jj==r) v+=aj[12];
        h16 hh,ll; split2(v,hh,ll); h4[jj]=hh; l4[jj]=ll;
      }
      h4_st(Ph,r,c4,h4); h4_st(Pl,r,c4,l4);
    }
  }
  __syncthreads();
  mmT<1,1,0>(Bh,Bl,Lh,Ll,0,acc,lane,wv); __syncthreads(); // W = L2 L = L^3
  stS(Bh,Bl,acc,dI,lane,wv,1.f,0.f); __syncthreads();     // B = W
  #pragma unroll
  for(int i=3;i>=0;i--){
    mmT<1,1,0>(Ph,Pl,Bh,Bl,0,acc,lane,wv);
    #pragma unroll
    for(int rt=0;rt<2;rt++)
      #pragma unroll
      for(int ct=0;ct<2;ct++)
        #pragma unroll
        for(int r=0;r<4;r++)
          acc[rt][ct][r]+=aj[3*i]*dI[rt][ct][r]+aj[3*i+1]*lv[rt][ct][r]+aj[3*i+2]*l2v[rt][ct][r];
    __syncthreads();
    stS(Ph,Pl,acc,dI,lane,wv,1.f,0.f);
    __syncthreads();
  }
}

// ---------------- coupled NS sqrt (full split; only 1-block kernels) -------
__device__ void ns_sqrt3(h16* Yh,h16* Yl,h16* Zh,h16* Zl,h16* Th,h16* Tl,
                         const float (*dI)[2][4], int tid,int lane,int wv){
  {
    int r=tid>>2;
    h16 oh,ol; split2(1.f,oh,ol);
    #pragma unroll
    for(int q=0;q<4;q++){
      int c4=(tid&3)*16+q*4;
      h16x4 h4={(h16)0,(h16)0,(h16)0,(h16)0};
      h16x4 l4={(h16)0,(h16)0,(h16)0,(h16)0};
      #pragma unroll
      for(int j=0;j<4;j++) if (c4+j==r){ h4[j]=oh; l4[j]=ol; }
      h4_st(Zh,r,c4,h4); h4_st(Zl,r,c4,l4);
    }
  }
  __syncthreads();
  f32x4 aY[2][2], aZ[2][2];
  for(int it=0; it<NSC_IT; it++){
    mmT<1,1,0>(Zh,Zl,Yh,Yl,0,aY,lane,wv); __syncthreads();
    stS(Th,Tl,aY,dI,lane,wv,-0.5f,1.5f); __syncthreads(); // U = 1.5I - 0.5 Z Y
    mmT<1,1,0>(Yh,Yl,Th,Tl,0,aY,lane,wv);                 // Y U
    mmT<1,1,0>(Th,Tl,Zh,Zl,0,aZ,lane,wv);                 // U Z
    __syncthreads();
    stS(Yh,Yl,aY,dI,lane,wv,1.f,0.f);
    stS(Zh,Zl,aZ,dI,lane,wv,1.f,0.f);
    __syncthreads();
  }
}

#define DECL_DI(dIname) \
  float dIname[2][2][4]; \
  { int rb_=(wv&1)*32, cb_=(wv>>1)*32; \
    _Pragma("unroll") \
    for(int rt=0;rt<2;rt++) \
      _Pragma("unroll") \
      for(int ct=0;ct<2;ct++) \
        _Pragma("unroll") \
        for(int r=0;r<4;r++) \
          dIname[rt][ct][r]=((rb_+16*rt+(lane>>4)*4+r)==(cb_+16*ct+(lane&15)))?1.f:0.f; }

// ---------------- kernels ----------------

// BiMap via split-MFMA + logm(S1)
__global__ __launch_bounds__(256) void kA(const float* __restrict__ Xg, const float* alphaP,
    const float* __restrict__ Wg, float* S1g, float* R2){
  __shared__ __align__(16) char lds[65536];
  int tid=threadIdx.x, b=blockIdx.x, lane=tid&63, wv=tid>>6;
  int lr=lane&15, lg=lane>>4;
  DECL_DI(dI);
  const float* Xb = Xg + (size_t)b*16384;
  h16* Wph=(h16*)lds;         h16* Wpl=Wph+8192;   // [64][128] planes, 32KB
  h16* Tph=(h16*)(lds+32768); h16* Tpl=Tph+8192;   // [64][128] planes, 32KB
  { // stage W planes: Wp[n][k] = W[k][n]
    int k0=tid>>1, nh=(tid&1)*32;
    const float* wr = Wg + k0*64 + nh;
    #pragma unroll
    for(int q=0;q<8;q++){
      float4 u=ld4(wr+q*4);
      float uu[4]={u.x,u.y,u.z,u.w};
      #pragma unroll
      for(int j=0;j<4;j++){
        int n=nh+q*4+j;
        h16 hh,ll; split2(uu[j],hh,ll);
        int off=(n*256+k0*2)^((n&7)<<4);
        *(h16*)((char*)Wph+off)=hh;
        *(h16*)((char*)Wpl+off)=ll;
      }
    }
  }
  float tv=(tid<128)? Xb[tid*129]:0.f;
  // trace reduce uses T-plane region (free at this point)
  float tr=block_sum(tv,(float*)(lds+32768),tid);   // also syncs W staging
  float al=alphaP[0];
  float f1=1.f/(tr+1e-4f);
  float scl=(1.f-al)*f1;
  float shift=al*(tr*f1)*(1.f/128.f);
  // ---- phase 1a: T = X W (A-frags streamed from global, split on the fly)
  f32x4 aM[2][4], aC[2][4];
  const f32x4 vz={0.f,0.f,0.f,0.f};
  #pragma unroll
  for(int rt=0;rt<2;rt++)
    #pragma unroll
    for(int ct=0;ct<4;ct++){ aM[rt][ct]=vz; aC[rt][ct]=vz; }
  int mb=wv*32;
  for(int ks=0;ks<4;ks++){
    h16x8 xah[2], xal[2];
    #pragma unroll
    for(int rt=0;rt<2;rt++){
      const float* px=Xb+(size_t)(mb+16*rt+lr)*128+ks*32+lg*8;
      float4 u0=ld4(px), u1=ld4(px+4);
      float uv[8]={u0.x,u0.y,u0.z,u0.w,u1.x,u1.y,u1.z,u1.w};
      #pragma unroll
      for(int e=0;e<8;e++){ h16 hh,ll; split2(uv[e],hh,ll); xah[rt][e]=hh; xal[rt][e]=ll; }
    }
    #pragma unroll
    for(int ct=0;ct<4;ct++){
      h16x8 bh=frag_ld2(Wph,ct*16+lr,ks,lg);
      h16x8 bl=frag_ld2(Wpl,ct*16+lr,ks,lg);
      #pragma unroll
      for(int rt=0;rt<2;rt++){
        aM[rt][ct]=__builtin_amdgcn_mfma_f32_16x16x32_f16(xah[rt],bh,aM[rt][ct],0,0,0);
        aC[rt][ct]=__builtin_amdgcn_mfma_f32_16x16x32_f16(xal[rt],bh,aC[rt][ct],0,0,0);
        aC[rt][ct]=__builtin_amdgcn_mfma_f32_16x16x32_f16(xah[rt],bl,aC[rt][ct],0,0,0);
      }
    }
  }
  __syncthreads();                 // trace reduce done before T-store reuse
  #pragma unroll
  for(int rt=0;rt<2;rt++){    // store T planes [n][k=m]
    int i0=mb+16*rt+lg*4;
    #pragma unroll
    for(int ct=0;ct<4;ct++){
      int j=ct*16+lr;
      h16x4 h4,l4;
      #pragma unroll
      for(int r=0;r<4;r++){
        float x=aM[rt][ct][r]+aC[rt][ct][r]*SPLIT_R;
        h16 hh,ll; split2(x,hh,ll); h4[r]=hh; l4[r]=ll;
      }
      int off=(j*256+i0*2)^((j&7)<<4);
      *(h16x4*)((char*)Tph+off)=h4;
      *(h16x4*)((char*)Tpl+off)=l4;
    }
  }
  __syncthreads();
  // ---- phase 1b: M0 = W^T T
  f32x4 sM[2][2], sC[2][2];
  #pragma unroll
  for(int rt=0;rt<2;rt++){ sM[rt][0]=vz; sM[rt][1]=vz; sC[rt][0]=vz; sC[rt][1]=vz; }
  int rb=(wv&1)*32, cb=(wv>>1)*32;
  for(int ks=0;ks<4;ks++){
    h16x8 ah2[2], al2[2];
    #pragma unroll
    for(int rt=0;rt<2;rt++){
      ah2[rt]=frag_ld2(Wph,rb+16*rt+lr,ks,lg);
      al2[rt]=frag_ld2(Wpl,rb+16*rt+lr,ks,lg);
    }
    #pragma unroll
    for(int ct=0;ct<2;ct++){
      h16x8 bh=frag_ld2(Tph,cb+16*ct+lr,ks,lg);
      h16x8 bl=frag_ld2(Tpl,cb+16*ct+lr,ks,lg);
      #pragma unroll
      for(int rt=0;rt<2;rt++){
        sM[rt][ct]=__builtin_amdgcn_mfma_f32_16x16x32_f16(ah2[rt],bh,sM[rt][ct],0,0,0);
        sC[rt][ct]=__builtin_amdgcn_mfma_f32_16x16x32_f16(al2[rt],bh,sC[rt][ct],0,0,0);
        sC[rt][ct]=__builtin_amdgcn_mfma_f32_16x16x32_f16(ah2[rt],bl,sC[rt][ct],0,0,0);
      }
    }
  }
  f32x4 accS[2][2];
  #pragma unroll
  for(int rt=0;rt<2;rt++)
    #pragma unroll
    for(int ct=0;ct<2;ct++) accS[rt][ct]=sM[rt][ct]+sC[rt][ct]*SPLIT_R;
  __syncthreads();                 // all Wp/Tp reads done before slot reuse
  st_gl(S1g+(size_t)b*4096, accS, lane,wv, scl, shift);   // S1 = scl*M0+shift*I
  h16* Ah=(h16*)lds;          h16* Al=Ah+4096;
  h16* Xh=(h16*)(lds+16384);  h16* Xl=Xh+4096;
  h16* Th=(h16*)(lds+32768);  h16* Tl=Th+4096;
  float* red=(float*)(lds+49152);                         // 4th 16KB slot free
  stS(Ah,Al,accS,dI,lane,wv, scl, shift + C1);            // A = S1 + C1*I
  __syncthreads();
  f32x4 aL[2][2];
  h16* parkh=(h16*)(R2+(size_t)b*4096);
  logm3(Ah,Al,Xh,Xl,Th,Tl,parkh,red,dI, C1, 11, 30, tid,lane,wv, aL);
  __syncthreads();
  st_gl(R2+(size_t)b*4096, aL, lane,wv, 2.f, LNC1);       // L1 = 2 P R + ln(c) I
}

// column-mean over batch (unchanged)
__global__ __launch_bounds__(256) void kRed(const float* __restrict__ R2, float* outM, float scale){
  __shared__ float red[256];
  int tid=threadIdx.x; int ee=tid&31; int sl=tid>>5;
  int e0 = blockIdx.x*32 + ee;
  float s=0.f;
  for(int j=0;j<256;j++) s += R2[(size_t)(sl+8*j)*4096 + e0];
  red[tid]=s; __syncthreads();
  if (sl<4) red[tid]+=red[tid+128];
  __syncthreads();
  if (sl<2) red[tid]+=red[tid+64];
  __syncthreads();
  if (sl==0) outM[e0] = (red[tid]+red[tid+32])*scale;
}

// G0^{+-1/2} = exp(+-Lbar/2); Bs = sqrt(sym(bn_bias))
__global__ __launch_bounds__(256) void kB(const float* Lbar, const float* biasP,
     float* Gi0, float* Gs0, float* Bs){
  __shared__ __align__(16) char lds[50176];
  int tid=threadIdx.x, lane=tid&63, wv=tid>>6;
  DECL_DI(dI);
  h16* s0h=(h16*)lds;          h16* s0l=s0h+4096;
  h16* s1h=(h16*)(lds+16384);  h16* s1l=s1h+4096;
  h16* s2h=(h16*)(lds+32768);  h16* s2l=s2h+4096;
  float* red=(float*)(lds+49152);
  float tr = block_sum((tid<64)? Lbar[tid*65]:0.f, red, tid);
  float cb_ = tr*(1.f/64.f);
  fill_gl(s0h,s0l, Lbar, 0.5f, -cb_, tid);                // D/2
  __syncthreads();
  exp3(s0h,s0l,s1h,s1l,s2h,s2l, dI, 1.f, tid,lane,wv);
  plane_out(s2h,s2l, Gs0, expf(0.5f*cb_), tid);
  __syncthreads();
  exp3(s0h,s0l,s1h,s1l,s2h,s2l, dI, -1.f, tid,lane,wv);
  plane_out(s2h,s2l, Gi0, expf(-0.5f*cb_), tid);
  __syncthreads();
  float tb = block_sum((tid<64)? biasP[tid*65]:0.f, red, tid);
  float itb=1.f/tb;
  { // Y = sym(bias)/tb -> s0
    int r=tid>>2;
    #pragma unroll
    for(int q=0;q<4;q++){
      int c4=(tid&3)*16+q*4;
      float4 v=ld4(biasP + r*64 + c4);
      float vv[4]={v.x,v.y,v.z,v.w};
      h16x4 h4,l4;
      #pragma unroll
      for(int j=0;j<4;j++){
        float x = 0.5f*(vv[j] + biasP[(c4+j)*64 + r]) * itb;
        h16 hh,ll; split2(x,hh,ll); h4[j]=hh; l4[j]=ll;
      }
      h4_st(s0h,r,c4,h4); h4_st(s0l,r,c4,l4);
    }
  }
  __syncthreads();
  ns_sqrt3(s0h,s0l,s1h,s1l,s2h,s2l, dI, tid,lane,wv);
  plane_out(s0h,s0l, Bs, sqrtf(tb), tid);
}

// Karcher-step log: M = Gi S1 Gi ; L = logm(M) -> R2 ; optional v accumulation
__global__ __launch_bounds__(256,3) void kC(const float* __restrict__ S1g, const float* GiP,
     float* R2, float* vpart, int doV){
  __shared__ __align__(16) char lds[50176];
  int tid=threadIdx.x, b=blockIdx.x, lane=tid&63, wv=tid>>6;
  DECL_DI(dI);
  h16* s0h=(h16*)lds;          h16* s0l=s0h+4096;
  h16* s1h=(h16*)(lds+16384);  h16* s1l=s1h+4096;
  h16* s2h=(h16*)(lds+32768);  h16* s2l=s2h+4096;
  float* red=(float*)(lds+49152);
  fill_gl(s0h,s0l, S1g+(size_t)b*4096, 1.f,0.f, tid);
  fill_gl(s1h,s1l, GiP, 1.f,0.f, tid);
  __syncthreads();
  f32x4 acc[2][2];
  mmT<1,1,0>(s0h,s0l,s1h,s1l,0,acc,lane,wv); __syncthreads();  // S1 Gi
  stS(s2h,s2l,acc,dI,lane,wv,1.f,0.f); __syncthreads();
  mmT<1,1,0>(s1h,s1l,s2h,s2l,0,acc,lane,wv); __syncthreads();  // M = Gi S1 Gi
  stS(s0h,s0l,acc,dI,lane,wv,1.f,1.f); __syncthreads();        // A = M + I
  f32x4 aL[2][2];
  h16* parkh=(h16*)(R2+(size_t)b*4096);
  logm3(s0h,s0l,s1h,s1l,s2h,s2l,parkh,red,dI, 1.f, 11, 30, tid,lane,wv, aL);
  __syncthreads();
  st_gl(R2+(size_t)b*4096, aL, lane,wv, 2.f, 0.f);
  if (doV){
    float s=0.f;
    #pragma unroll
    for(int rt=0;rt<2;rt++)
      #pragma unroll
      for(int ct=0;ct<2;ct++)
        #pragma unroll
        for(int r=0;r<4;r++){ float lv=2.f*aL[rt][ct][r]; s=fmaf(lv,lv,s); }
    __syncthreads();
    s = block_sum(s, red, tid);
    if (tid==0) atomicAdd(vpart + (b&31), s);
  }
}

// G_new = Gs exp(Ebar) Gs ; then G_new^{+-1/2}
__global__ __launch_bounds__(256) void kD(const float* Ebar, const float* GsP,
     float* GsN, float* GiN){
  __shared__ __align__(16) char lds[50176];
  int tid=threadIdx.x, lane=tid&63, wv=tid>>6;
  DECL_DI(dI);
  h16* s0h=(h16*)lds;          h16* s0l=s0h+4096;
  h16* s1h=(h16*)(lds+16384);  h16* s1l=s1h+4096;
  h16* s2h=(h16*)(lds+32768);  h16* s2l=s2h+4096;
  float* red=(float*)(lds+49152);
  fill_gl(s0h,s0l, Ebar, 1.f,0.f, tid); __syncthreads();
  exp3(s0h,s0l,s1h,s1l,s2h,s2l, dI, 1.f, tid,lane,wv);   // E in s2
  fill_gl(s0h,s0l, GsP, 1.f,0.f, tid);                   // Gs over Ebar
  __syncthreads();
  f32x4 acc[2][2];
  mmT<1,1,0>(s2h,s2l,s0h,s0l,0,acc,lane,wv); __syncthreads();  // E Gs
  stS(s1h,s1l,acc,dI,lane,wv,1.f,0.f); __syncthreads();
  mmT<1,1,0>(s0h,s0l,s1h,s1l,0,acc,lane,wv);                   // G = Gs (E Gs)
  float tv=0.f;
  #pragma unroll
  for(int rt=0;rt<2;rt++)
    #pragma unroll
    for(int ct=0;ct<2;ct++)
      #pragma unroll
      for(int r=0;r<4;r++) tv += acc[rt][ct][r]*dI[rt][ct][r];
  float t = block_sum(tv, red, tid);
  stS(s0h,s0l,acc,dI,lane,wv,1.f/t,0.f); __syncthreads();
  ns_sqrt3(s0h,s0l,s1h,s1l,s2h,s2l, dI, tid,lane,wv);
  float st_=sqrtf(t), ist=1.f/st_;
  plane_out(s0h,s0l, GsN, st_, tid);
  plane_out(s1h,s1l, GiN, ist, tid);
}

__global__ void kF2(const float* vpart, const float* gammaP, float* sOut){
  if (threadIdx.x==0 && blockIdx.x==0){
    float v=0.f;
    for(int i=0;i<32;i++) v+=vpart[i];
    v *= (1.f/2048.f);
    sOut[0] = gammaP[0] / sqrtf(v + 1e-5f);
  }
}

// Y=exp(s Lt); Z=Bs Y Bs; Lg=logm(Z); out = triu(Lg)*coef @ Wc^T + bc
__global__ __launch_bounds__(256,3) void kG(float* R2, const float* BsP, const float* sP,
     const float* __restrict__ WcP, const float* bcP, float* outP){
  __shared__ __align__(16) char lds[50176];
  int tid=threadIdx.x, b=blockIdx.x, lane=tid&63, wv=tid>>6;
  DECL_DI(dI);
  h16* s0h=(h16*)lds;          h16* s0l=s0h+4096;
  h16* s1h=(h16*)(lds+16384);  h16* s1l=s1h+4096;
  h16* s2h=(h16*)(lds+32768);  h16* s2l=s2h+4096;
  float* red=(float*)(lds+49152);
  fill_gl(s0h,s0l, R2+(size_t)b*4096, 1.f,0.f, tid); __syncthreads();  // Lt
  float s = sP[0];
  exp3(s0h,s0l,s1h,s1l,s2h,s2l, dI, s, tid,lane,wv);     // Y in s2
  fill_gl(s0h,s0l, BsP, 1.f,0.f, tid);                   // Bs over Lt
  __syncthreads();
  f32x4 acc[2][2];
  mmT<1,1,0>(s2h,s2l,s0h,s0l,0,acc,lane,wv); __syncthreads();  // Y Bs
  stS(s1h,s1l,acc,dI,lane,wv,1.f,0.f); __syncthreads();
  mmT<1,1,0>(s0h,s0l,s1h,s1l,0,acc,lane,wv); __syncthreads();  // Z = Bs Y Bs
  stS(s2h,s2l,acc,dI,lane,wv,1.f,1.f); __syncthreads();        // A = Z + I
  f32x4 aL[2][2];
  h16* parkh=(h16*)(R2+(size_t)b*4096);
  logm3(s2h,s2l,s0h,s0l,s1h,s1l,parkh,red,dI, 1.f, 6, 15, tid,lane,wv, aL);
  // epilogue: triu(2*P*R) * coef @ Wc^T
  float o0=0,o1=0,o2=0,o3=0;
  {
    int lr=lane&15, lq=lane>>4, rb=(wv&1)*32, cb=(wv>>1)*32;
    #pragma unroll
    for(int rt=0;rt<2;rt++)
      #pragma unroll
      for(int ct=0;ct<2;ct++)
        #pragma unroll
        for(int r=0;r<4;r++){
          int i=rb+16*rt+lq*4+r, j=cb+16*ct+lr;
          float lg2=2.f*aL[rt][ct][r];
          int a=(i<j)? i:j, bb=(i<j)? j:i;
          int tri = a*64 - ((a*(a-1))>>1) + (bb-a);
          float w = (i==j)? lg2 : lg2*0.70710678118654752f;
          o0=fmaf(w, WcP[tri],      o0);
          o1=fmaf(w, WcP[2080+tri], o1);
          o2=fmaf(w, WcP[4160+tri], o2);
          o3=fmaf(w, WcP[6240+tri], o3);
        }
  }
  __syncthreads();
  float* redv=(float*)lds;
  float4 pk; pk.x=o0; pk.y=o1; pk.z=o2; pk.w=o3;
  st4(redv+4*tid, pk); __syncthreads();
  for(int off=128; off>0; off>>=1){
    if (tid<off){
      float4 x=ld4(redv+4*tid), y=ld4(redv+4*(tid+off));
      x.x+=y.x; x.y+=y.y; x.z+=y.z; x.w+=y.w;
      st4(redv+4*tid, x);
    }
    __syncthreads();
  }
  if (tid==0){
    outP[b*4+0]=redv[0]+bcP[0];
    outP[b*4+1]=redv[1]+bcP[1];
    outP[b*4+2]=redv[2]+bcP[2];
    outP[b*4+3]=redv[3]+bcP[3];
  }
}

extern "C" void kernel_launch(void* const* d_in, const int* in_sizes, int n_in,
                              void* d_out, int out_size, void* d_ws, size_t ws_size,
                              hipStream_t stream){
  const float* X     = (const float*)d_in[0];
  const float* alpha = (const float*)d_in[1];
  const float* W     = (const float*)d_in[2];
  const float* gamma = (const float*)d_in[3];
  const float* bias  = (const float*)d_in[4];
  const float* Wc    = (const float*)d_in[5];
  const float* bc    = (const float*)d_in[6];
  float* ws = (float*)d_ws;
  float* S1 = ws + WS_S1;
  float* R2 = ws + WS_R2;
  float* sm = ws + WS_SM;

  hipMemsetAsync(sm + SM_VPART, 0, 33*sizeof(float), stream);

  kA  <<<2048,256,0,stream>>>(X, alpha, W, S1, R2);
  kRed<<<128, 256,0,stream>>>(R2, sm+SM_LBAR, 1.f/2048.f);
  kB  <<<1,   256,0,stream>>>(sm+SM_LBAR, bias, sm+SM_GI0, sm+SM_GS0, sm+SM_BS);
  kC  <<<2048,256,0,stream>>>(S1, sm+SM_GI0, R2, nullptr, 0);
  kRed<<<128, 256,0,stream>>>(R2, sm+SM_EBAR1, 1.f/2048.f);
  kD  <<<1,   256,0,stream>>>(sm+SM_EBAR1, sm+SM_GS0, sm+SM_GS1, sm+SM_GI1);
  kC  <<<2048,256,0,stream>>>(S1, sm+SM_GI1, R2, nullptr, 0);
  kRed<<<128, 256,0,stream>>>(R2, sm+SM_EBAR2, 1.f/2048.f);
  kD  <<<1,   256,0,stream>>>(sm+SM_EBAR2, sm+SM_GS1, sm+SM_GS2, sm+SM_GI2);
  kC  <<<2048,256,0,stream>>>(S1, sm+SM_GI2, R2, sm+SM_VPART, 1);
  kF2 <<<1,1,0,stream>>>(sm+SM_VPART, gamma, sm+SM_S);
  kG  <<<2048,256,0,stream>>>(R2, sm+SM_BS, sm+SM_S, Wc, bc, (float*)d_out);
}

// Round 4
// 778.814 us; speedup vs baseline: 5.4424x; 1.1853x over previous
//
#include <hip/hip_runtime.h>
#include <math.h>

// ============================================================================
// SPDNet forward, eig-free — v4:
//  * chunk-4 Paterson-Stockmeyer logm (powers snapped to regs from acc)
//  * kA: series J=15 (|R|<=0.71 known spectrum), NS with 1 split iter
//  * single-barrier matmul phases via slot cycling (hi-NS ping-pong through
//    dead lo-planes; poly P ping-pong T<->X; diag-shift fused into NS tail)
//  * exp4: non-L-preserving single-barrier exp (result lands back in L slot)
// Split scheme: v = hi + lo/4096 (f16,f16), 3 MFMAs = fp32-class accuracy.
// Planes store TRANSPOSE of semantic matrix; mm(L,R) = L^T R (left ops symm).
// ============================================================================

#define NSC_IT  12
#define C1      0.0038729833f
#define LNC1    (-5.553730f)
#define SPLIT_S 4096.f
#define SPLIT_R (1.f/4096.f)

typedef _Float16 h16;
typedef _Float16 h16x8 __attribute__((ext_vector_type(8)));
typedef _Float16 h16x4 __attribute__((ext_vector_type(4)));
typedef float    f32x4 __attribute__((ext_vector_type(4)));

// ws layout (floats)
#define WS_S1   ((size_t)0)
#define WS_R2   ((size_t)8388608)
#define WS_SM   ((size_t)16777216)
#define SM_LBAR  0
#define SM_EBAR1 4096
#define SM_EBAR2 8192
#define SM_GI0   12288
#define SM_GS0   16384
#define SM_GI1   20480
#define SM_GS1   24576
#define SM_GI2   28672
#define SM_GS2   32768
#define SM_BS    36864
#define SM_VPART 40960
#define SM_S     40992

__device__ __forceinline__ float4 ld4(const float* p){ return *(const float4*)p; }
__device__ __forceinline__ void  st4(float* p, float4 v){ *(float4*)p = v; }

// ---------------- split-f16 plane helpers (64x64, 128B row stride) ---------
__device__ __forceinline__ int eoff(int r, int c){ return (r*128 + c*2) ^ ((r&7)<<4); }

__device__ __forceinline__ h16x8 frag_ld(const h16* p, int row, int ks, int lg){
  int off = (row*128 + ks*64 + lg*16) ^ ((row&7)<<4);
  return *(const h16x8*)((const char*)p + off);
}
// 64x128 plane (256B row stride), ks in 0..3
__device__ __forceinline__ h16x8 frag_ld2(const h16* p, int row, int ks, int lg){
  int off = (row*256 + ks*64 + lg*16) ^ ((row&7)<<4);
  return *(const h16x8*)((const char*)p + off);
}
__device__ __forceinline__ h16x4 h4_ld(const h16* p, int r, int c4){
  return *(const h16x4*)((const char*)p + eoff(r,c4));
}
__device__ __forceinline__ void h4_st(h16* p, int r, int c4, h16x4 v){
  *(h16x4*)((char*)p + eoff(r,c4)) = v;
}
__device__ __forceinline__ void split2(float v, h16& h, h16& l){
  h16 hh = (h16)v;
  h = hh;
  l = (h16)((v - (float)hh) * SPLIT_S);
}
__device__ __forceinline__ float join2(h16 h, h16 l){
  return (float)h + (float)l * SPLIT_R;
}

// ---------------- MFMA 64x64x64: D = L^T * R ------------------------------
// AS/BS: whether left/right lo-planes participate. GP: B from global (linear).
template<int AS,int BS,int GP>
__device__ __forceinline__ void mmT(const h16* Lh,const h16* Ll,
                                    const h16* Rh,const h16* Rl,const h16* gR,
                                    f32x4 acc[2][2], int lane,int wv){
  const int lr=lane&15, lg=lane>>4;
  const int rb=(wv&1)*32, cb=(wv>>1)*32;
  h16x8 ah[2][2], al[2][2];
  #pragma unroll
  for(int rt=0;rt<2;rt++){
    #pragma unroll
    for(int ks=0;ks<2;ks++){
      ah[rt][ks]=frag_ld(Lh, rb+16*rt+lr, ks, lg);
      if(AS) al[rt][ks]=frag_ld(Ll, rb+16*rt+lr, ks, lg);
    }
  }
  f32x4 aM[2][2], aC[2][2];
  const f32x4 vz={0.f,0.f,0.f,0.f};
  #pragma unroll
  for(int rt=0;rt<2;rt++){ aM[rt][0]=vz; aM[rt][1]=vz; aC[rt][0]=vz; aC[rt][1]=vz; }
  #pragma unroll
  for(int ct=0;ct<2;ct++){
    #pragma unroll
    for(int ks=0;ks<2;ks++){
      h16x8 bh, bl;
      if(GP){
        const h16* g = gR + (cb+16*ct+lr)*64 + ks*32 + lg*8;
        bh = *(const h16x8*)g;
        if(BS) bl = *(const h16x8*)(g+4096);
      }else{
        bh = frag_ld(Rh, cb+16*ct+lr, ks, lg);
        if(BS) bl = frag_ld(Rl, cb+16*ct+lr, ks, lg);
      }
      #pragma unroll
      for(int rt=0;rt<2;rt++){
        aM[rt][ct]=__builtin_amdgcn_mfma_f32_16x16x32_f16(ah[rt][ks],bh,aM[rt][ct],0,0,0);
        if(AS) aC[rt][ct]=__builtin_amdgcn_mfma_f32_16x16x32_f16(al[rt][ks],bh,aC[rt][ct],0,0,0);
        if(BS) aC[rt][ct]=__builtin_amdgcn_mfma_f32_16x16x32_f16(ah[rt][ks],bl,aC[rt][ct],0,0,0);
      }
    }
  }
  #pragma unroll
  for(int rt=0;rt<2;rt++)
    #pragma unroll
    for(int ct=0;ct<2;ct++)
      acc[rt][ct] = (AS||BS) ? (aM[rt][ct] + aC[rt][ct]*SPLIT_R) : aM[rt][ct];
}

// split store to plane (transposed): x = acc*scale + dadd*dI
__device__ __forceinline__ void stS(h16* Dh,h16* Dl,const f32x4 acc[2][2],
                                    const float (*dI)[2][4],
                                    int lane,int wv,float scale,float dadd){
  const int lr=lane&15, lg=lane>>4, rb=(wv&1)*32, cb=(wv>>1)*32;
  #pragma unroll
  for(int rt=0;rt<2;rt++){
    int i0=rb+16*rt+lg*4;
    #pragma unroll
    for(int ct=0;ct<2;ct++){
      int j=cb+16*ct+lr;
      h16x4 h4,l4;
      #pragma unroll
      for(int r=0;r<4;r++){
        float x=fmaf(acc[rt][ct][r],scale, dadd*dI[rt][ct][r]);
        h16 hh,ll; split2(x,hh,ll); h4[r]=hh; l4[r]=ll;
      }
      int off=(j*128+i0*2)^((j&7)<<4);
      *(h16x4*)((char*)Dh+off)=h4;
      *(h16x4*)((char*)Dl+off)=l4;
    }
  }
}
// hi-only store
__device__ __forceinline__ void stH(h16* Dh,const f32x4 acc[2][2],
                                    const float (*dI)[2][4],
                                    int lane,int wv,float scale,float dadd){
  const int lr=lane&15, lg=lane>>4, rb=(wv&1)*32, cb=(wv>>1)*32;
  #pragma unroll
  for(int rt=0;rt<2;rt++){
    int i0=rb+16*rt+lg*4;
    #pragma unroll
    for(int ct=0;ct<2;ct++){
      int j=cb+16*ct+lr;
      h16x4 h4;
      #pragma unroll
      for(int r=0;r<4;r++){
        float x=fmaf(acc[rt][ct][r],scale, dadd*dI[rt][ct][r]);
        h4[r]=(h16)x;
      }
      int off=(j*128+i0*2)^((j&7)<<4);
      *(h16x4*)((char*)Dh+off)=h4;
    }
  }
}

// store D to global f32 (outputs symmetric; transpose ok)
__device__ __forceinline__ void st_gl(float* G, const f32x4 acc[2][2],
                                      int lane,int wv,float scale,float dadd){
  const int lr=lane&15, lg=lane>>4, rb=(wv&1)*32, cb=(wv>>1)*32;
  #pragma unroll
  for(int rt=0;rt<2;rt++){
    int i0=rb+16*rt+lg*4;
    #pragma unroll
    for(int ct=0;ct<2;ct++){
      int j=cb+16*ct+lr;
      float4 v; float* vf=(float*)&v;
      #pragma unroll
      for(int r=0;r<4;r++){
        float x=acc[rt][ct][r]*scale;
        if (i0+r==j) x += dadd;
        vf[r]=x;
      }
      st4(G + j*64 + i0, v);
    }
  }
}

// park D to global split (hi at gh[0:4096], lo at gh[4096:8192]), linear
__device__ __forceinline__ void st_park(h16* gh, const f32x4 acc[2][2], int lane,int wv){
  const int lr=lane&15, lg=lane>>4, rb=(wv&1)*32, cb=(wv>>1)*32;
  #pragma unroll
  for(int rt=0;rt<2;rt++){
    int i0=rb+16*rt+lg*4;
    #pragma unroll
    for(int ct=0;ct<2;ct++){
      int j=cb+16*ct+lr;
      h16x4 h4,l4;
      #pragma unroll
      for(int r=0;r<4;r++){ h16 hh,ll; split2(acc[rt][ct][r],hh,ll); h4[r]=hh; l4[r]=ll; }
      *(h16x4*)(gh + j*64 + i0) = h4;
      *(h16x4*)(gh + 4096 + j*64 + i0) = l4;
    }
  }
}

// snapshot plane values at this thread's D positions into registers
__device__ __forceinline__ void snap(const h16* Ph,const h16* Pl,float (*v)[2][4],
                                     int lane,int wv){
  const int lr=lane&15, lg=lane>>4, rb=(wv&1)*32, cb=(wv>>1)*32;
  #pragma unroll
  for(int rt=0;rt<2;rt++){
    int i0=rb+16*rt+lg*4;
    #pragma unroll
    for(int ct=0;ct<2;ct++){
      int j=cb+16*ct+lr;
      h16x4 h=h4_ld(Ph,j,i0), l=h4_ld(Pl,j,i0);
      #pragma unroll
      for(int r=0;r<4;r++) v[rt][ct][r]=join2(h[r],l[r]);
    }
  }
}

// snapshot acc into registers (same D positions, no LDS traffic)
__device__ __forceinline__ void snapa(float (*v)[2][4], const f32x4 acc[2][2]){
  #pragma unroll
  for(int rt=0;rt<2;rt++)
    #pragma unroll
    for(int ct=0;ct<2;ct++)
      #pragma unroll
      for(int r=0;r<4;r++) v[rt][ct][r]=acc[rt][ct][r];
}

__device__ __forceinline__ void addK4(f32x4 acc[2][2], const float (*dI)[2][4],
    const float (*sv)[2][4], const float (*s2v)[2][4], const float (*s3v)[2][4],
    float a0,float a1,float a2,float a3){
  #pragma unroll
  for(int rt=0;rt<2;rt++)
    #pragma unroll
    for(int ct=0;ct<2;ct++)
      #pragma unroll
      for(int r=0;r<4;r++)
        acc[rt][ct][r] += a0*dI[rt][ct][r] + a1*sv[rt][ct][r]
                        + a2*s2v[rt][ct][r] + a3*s3v[rt][ct][r];
}

__device__ __forceinline__ void addK3(f32x4 acc[2][2], const float (*dI)[2][4],
    const float (*lv)[2][4], const float (*l2v)[2][4],
    float a0,float a1,float a2){
  #pragma unroll
  for(int rt=0;rt<2;rt++)
    #pragma unroll
    for(int ct=0;ct<2;ct++)
      #pragma unroll
      for(int r=0;r<4;r++)
        acc[rt][ct][r] += a0*dI[rt][ct][r] + a1*lv[rt][ct][r] + a2*l2v[rt][ct][r];
}

// fill planes from global f32 symmetric: x = (v + dshift_on_diag)*scale
__device__ __forceinline__ void fill_gl(h16* Ph, h16* Pl, const float* g,
                                        float scale, float dshift, int tid){
  int r = tid>>2;
  #pragma unroll
  for(int q=0;q<4;q++){
    int c4 = (tid&3)*16 + q*4;
    float4 v = ld4(g + r*64 + c4);
    float vv[4]={v.x,v.y,v.z,v.w};
    h16x4 h4,l4;
    #pragma unroll
    for(int j=0;j<4;j++){
      float x = vv[j];
      if (c4+j == r) x += dshift;
      x *= scale;
      h16 hh,ll; split2(x,hh,ll); h4[j]=hh; l4[j]=ll;
    }
    h4_st(Ph,r,c4,h4); h4_st(Pl,r,c4,l4);
  }
}

__device__ __forceinline__ void plane_out(const h16* Ph, const h16* Pl, float* g,
                                          float scale, int tid){
  int r=tid>>2;
  #pragma unroll
  for(int q=0;q<4;q++){
    int c4=(tid&3)*16+q*4;
    h16x4 h4=h4_ld(Ph,r,c4), l4=h4_ld(Pl,r,c4);
    float4 v;
    v.x=join2(h4[0],l4[0])*scale;
    v.y=join2(h4[1],l4[1])*scale;
    v.z=join2(h4[2],l4[2])*scale;
    v.w=join2(h4[3],l4[3])*scale;
    st4(g + r*64 + c4, v);
  }
}

__device__ __forceinline__ void diag_add(h16* Ph, h16* Pl, float add, int tid){
  if (tid<64){
    int off = (tid*128 + tid*2) ^ ((tid&7)<<4);
    h16* ph = (h16*)((char*)Ph + off);
    h16* pl = (h16*)((char*)Pl + off);
    float v = join2(*ph,*pl) + add;
    h16 hh,ll; split2(v,hh,ll);
    *ph=hh; *pl=ll;
  }
}

__device__ float block_sum(float v, float* red, int tid){
  red[tid]=v; __syncthreads();
  for(int off=128; off>0; off>>=1){
    if (tid<off) red[tid]+=red[tid+off];
    __syncthreads();
  }
  float r=red[0]; __syncthreads();
  return r;
}

__device__ __forceinline__ float cfj(int j, int J){
  return (j<=J)? 1.f/(float)(2*j+1) : 0.f;
}

// ---------------- Newton-Schulz inverse: 5 hi ping-pong + NSS split --------
// On exit: X = A^-1 (split); A gets postshift added to its diagonal.
// Hi iterations ping-pong X/T through the (dead) lo planes -> 1 barrier/phase.
template<int NSS>
__device__ void ns_inv4(h16* Ah,h16* Al,h16* Xh,h16* Xl,h16* Th,h16* Tl,
                        float* red,const float (*dI)[2][4],
                        int tid,int lane,int wv,float lminB,float postshift){
  { // ||A||_inf from hi plane
    int row=tid>>2, seg=tid&3;
    float s=0.f;
    #pragma unroll
    for(int q=0;q<4;q++){
      h16x4 h4 = h4_ld(Ah,row,seg*16+q*4);
      #pragma unroll
      for(int j=0;j<4;j++) s += fabsf((float)h4[j]);
    }
    red[tid]=s*1.001f; __syncthreads();
    if((tid&3)==0) red[tid]=red[tid]+red[tid+1]+red[tid+2]+red[tid+3];
    __syncthreads();
    if(tid==0){ float m=0.f; for(int i=0;i<64;i++) m=fmaxf(m,red[4*i]); red[0]=m; }
    __syncthreads();
  }
  float alpha = 2.f/(lminB + red[0]);
  { // X0 = alpha*I (hi only) into Xh
    int r=tid>>2;
    h16 ahh=(h16)alpha;
    #pragma unroll
    for(int q=0;q<4;q++){
      int c4=(tid&3)*16+q*4;
      h16x4 h4={(h16)0,(h16)0,(h16)0,(h16)0};
      #pragma unroll
      for(int j=0;j<4;j++) if (c4+j==r) h4[j]=ahh;
      h4_st(Xh,r,c4,h4);
    }
  }
  __syncthreads();
  f32x4 acc[2][2];
  #pragma unroll
  for(int it=0;it<5;it++){
    const h16* Xa=(it&1)?Xl:Xh;
    h16* Ta=(it&1)?Tl:Th;
    h16* Xn=(it&1)?Xh:Xl;
    mmT<0,0,0>(Ah,0,Xa,0,0,acc,lane,wv);
    stH(Ta,acc,dI,lane,wv,-1.f,2.f); __syncthreads();   // T = 2I - A X
    mmT<0,0,0>(Xa,0,Ta,0,0,acc,lane,wv);
    stH(Xn,acc,dI,lane,wv,1.f,0.f); __syncthreads();    // X' = X T
  }
  // X-hi now lives in Xl space. Promote with split A (one split NS iter):
  mmT<1,0,0>(Ah,Al,Xl,0,0,acc,lane,wv);
  stS(Th,Tl,acc,dI,lane,wv,-1.f,2.f); __syncthreads();
  mmT<0,1,0>(Xl,0,Th,Tl,0,acc,lane,wv); __syncthreads(); // reads Xl -> barrier
  if(NSS>1){
    stS(Xh,Xl,acc,dI,lane,wv,1.f,0.f); __syncthreads();
    mmT<1,1,0>(Ah,Al,Xh,Xl,0,acc,lane,wv);
    stS(Th,Tl,acc,dI,lane,wv,-1.f,2.f); __syncthreads();
    mmT<1,1,0>(Xh,Xl,Th,Tl,0,acc,lane,wv); __syncthreads();
  }
  stS(Xh,Xl,acc,dI,lane,wv,1.f,0.f);
  diag_add(Ah,Al,postshift,tid);       // fused: A not read in this phase
  __syncthreads();
}

// ---------------- logm, chunk-4 PS. A holds M + cshift*I on entry. --------
// accOut = P*R ; caller: L = 2*accOut + ln(c)*I.
template<int C,int J,int NSS>
__device__ void logm4(h16* Ah,h16* Al,h16* Xh,h16* Xl,h16* Th,h16* Tl,
                      h16* parkh, float* red, const float (*dI)[2][4],
                      float cshift,int tid,int lane,int wv,
                      f32x4 accOut[2][2]){
  ns_inv4<NSS>(Ah,Al,Xh,Xl,Th,Tl,red,dI,tid,lane,wv,cshift,-2.f*cshift);
  f32x4 acc[2][2];
  mmT<1,1,0>(Ah,Al,Xh,Xl,0,acc,lane,wv);               // R = (A-2cI) X
  stS(Th,Tl,acc,dI,lane,wv,1.f,0.f);
  st_park(parkh,acc,lane,wv);
  __syncthreads();
  float sv[2][2][4], s2v[2][2][4], s3v[2][2][4];
  mmT<1,1,0>(Th,Tl,Th,Tl,0,acc,lane,wv);               // S = R^2 -> A
  snapa(sv,acc);
  stS(Ah,Al,acc,dI,lane,wv,1.f,0.f); __syncthreads();
  mmT<1,1,0>(Ah,Al,Ah,Al,0,acc,lane,wv);               // S2 -> X
  snapa(s2v,acc);
  stS(Xh,Xl,acc,dI,lane,wv,1.f,0.f); __syncthreads();
  mmT<1,1,0>(Xh,Xl,Ah,Al,0,acc,lane,wv);               // S3 = S2 S -> T
  snapa(s3v,acc);
  stS(Th,Tl,acc,dI,lane,wv,1.f,0.f); __syncthreads();
  mmT<1,1,0>(Xh,Xl,Xh,Xl,0,acc,lane,wv);               // W = S4 = S2^2 -> A
  stS(Ah,Al,acc,dI,lane,wv,1.f,0.f);
  { // P = K_{C-1} elementwise from snapped powers -> T (same phase as W)
    f32x4 p[2][2];
    float a0=cfj(4*(C-1),J),a1=cfj(4*(C-1)+1,J),a2=cfj(4*(C-1)+2,J),a3=cfj(4*(C-1)+3,J);
    #pragma unroll
    for(int rt=0;rt<2;rt++)
      #pragma unroll
      for(int ct=0;ct<2;ct++)
        #pragma unroll
        for(int r=0;r<4;r++)
          p[rt][ct][r]=a0*dI[rt][ct][r]+a1*sv[rt][ct][r]+a2*s2v[rt][ct][r]+a3*s3v[rt][ct][r];
    stS(Th,Tl,p,dI,lane,wv,1.f,0.f);
  }
  __syncthreads();
  #pragma unroll
  for(int k=0;k<C-1;k++){        // P = P*W + K_i, ping-pong T<->X
    int i=C-2-k;
    const h16 *Ph=(k&1)?Xh:Th; const h16 *Pl=(k&1)?Xl:Tl;
    h16 *Qh=(k&1)?Th:Xh; h16 *Ql=(k&1)?Tl:Xl;
    mmT<1,1,0>(Ph,Pl,Ah,Al,0,acc,lane,wv);
    addK4(acc,dI,sv,s2v,s3v,cfj(4*i,J),cfj(4*i+1,J),cfj(4*i+2,J),cfj(4*i+3,J));
    stS(Qh,Ql,acc,dI,lane,wv,1.f,0.f);
    __syncthreads();
  }
  // C-1 odd (C=4 or 8) -> P ends in X slot
  mmT<1,1,1>(Xh,Xl,(const h16*)0,(const h16*)0,parkh,accOut,lane,wv); // P R
}

// ---------------- exp(s*L): L in slot0 (destroyed), result in slot0 --------
__device__ void exp4(h16* Lh,h16* Ll, h16* Bh,h16* Bl, h16* Wh,h16* Wl,
                     const float (*dI)[2][4], float s, int tid,int lane,int wv){
  float aj[15]; aj[0]=1.f;
  #pragma unroll
  for(int j=1;j<15;j++) aj[j]=aj[j-1]*s/(float)j;
  float lv[2][2][4], l2v[2][2][4];
  snap(Lh,Ll,lv,lane,wv);
  f32x4 acc[2][2];
  mmT<1,1,0>(Lh,Ll,Lh,Ll,0,acc,lane,wv);               // L2 -> B
  snapa(l2v,acc);
  stS(Bh,Bl,acc,dI,lane,wv,1.f,0.f); __syncthreads();
  mmT<1,1,0>(Bh,Bl,Lh,Ll,0,acc,lane,wv);               // W = L3 -> W
  stS(Wh,Wl,acc,dI,lane,wv,1.f,0.f); __syncthreads();
  { // P init (deg 12..14) -> L slot (L dead)
    f32x4 p[2][2];
    #pragma unroll
    for(int rt=0;rt<2;rt++)
      #pragma unroll
      for(int ct=0;ct<2;ct++)
        #pragma unroll
        for(int r=0;r<4;r++)
          p[rt][ct][r]=aj[12]*dI[rt][ct][r]+aj[13]*lv[rt][ct][r]+aj[14]*l2v[rt][ct][r];
    stS(Lh,Ll,p,dI,lane,wv,1.f,0.f);
  }
  __syncthreads();
  #pragma unroll
  for(int k=0;k<4;k++){          // ping-pong L<->B ; ends in L
    int i=3-k;
    const h16 *Ph=(k&1)?Bh:Lh; const h16 *Pl=(k&1)?Bl:Ll;
    h16 *Qh=(k&1)?Lh:Bh; h16 *Ql=(k&1)?Ll:Bl;
    mmT<1,1,0>(Ph,Pl,Wh,Wl,0,acc,lane,wv);
    addK3(acc,dI,lv,l2v,aj[3*i],aj[3*i+1],aj[3*i+2]);
    stS(Qh,Ql,acc,dI,lane,wv,1.f,0.f);
    __syncthreads();
  }
}

// ---------------- coupled NS sqrt (full split; only 1-block kernels) -------
__device__ void ns_sqrt3(h16* Yh,h16* Yl,h16* Zh,h16* Zl,h16* Th,h16* Tl,
                         const float (*dI)[2][4], int tid,int lane,int wv){
  {
    int r=tid>>2;
    h16 oh,ol; split2(1.f,oh,ol);
    #pragma unroll
    for(int q=0;q<4;q++){
      int c4=(tid&3)*16+q*4;
      h16x4 h4={(h16)0,(h16)0,(h16)0,(h16)0};
      h16x4 l4={(h16)0,(h16)0,(h16)0,(h16)0};
      #pragma unroll
      for(int j=0;j<4;j++) if (c4+j==r){ h4[j]=oh; l4[j]=ol; }
      h4_st(Zh,r,c4,h4); h4_st(Zl,r,c4,l4);
    }
  }
  __syncthreads();
  f32x4 aY[2][2], aZ[2][2];
  for(int it=0; it<NSC_IT; it++){
    mmT<1,1,0>(Zh,Zl,Yh,Yl,0,aY,lane,wv); __syncthreads();
    stS(Th,Tl,aY,dI,lane,wv,-0.5f,1.5f); __syncthreads(); // U = 1.5I - 0.5 Z Y
    mmT<1,1,0>(Yh,Yl,Th,Tl,0,aY,lane,wv);                 // Y U
    mmT<1,1,0>(Th,Tl,Zh,Zl,0,aZ,lane,wv);                 // U Z
    __syncthreads();
    stS(Yh,Yl,aY,dI,lane,wv,1.f,0.f);
    stS(Zh,Zl,aZ,dI,lane,wv,1.f,0.f);
    __syncthreads();
  }
}

#define DECL_DI(dIname) \
  float dIname[2][2][4]; \
  { int rb_=(wv&1)*32, cb_=(wv>>1)*32; \
    _Pragma("unroll") \
    for(int rt=0;rt<2;rt++) \
      _Pragma("unroll") \
      for(int ct=0;ct<2;ct++) \
        _Pragma("unroll") \
        for(int r=0;r<4;r++) \
          dIname[rt][ct][r]=((rb_+16*rt+(lane>>4)*4+r)==(cb_+16*ct+(lane&15)))?1.f:0.f; }

// ---------------- kernels ----------------

// BiMap via split-MFMA + logm(S1) (C=4,J=15 valid: |R|<=0.71 by spectrum)
__global__ __launch_bounds__(256) void kA(const float* __restrict__ Xg, const float* alphaP,
    const float* __restrict__ Wg, float* S1g, float* R2){
  __shared__ __align__(16) char lds[65536];
  int tid=threadIdx.x, b=blockIdx.x, lane=tid&63, wv=tid>>6;
  int lr=lane&15, lg=lane>>4;
  DECL_DI(dI);
  const float* Xb = Xg + (size_t)b*16384;
  h16* Wph=(h16*)lds;         h16* Wpl=Wph+8192;   // [64][128] planes, 32KB
  h16* Tph=(h16*)(lds+32768); h16* Tpl=Tph+8192;   // [64][128] planes, 32KB
  { // stage W planes: Wp[n][k] = W[k][n]
    int k0=tid>>1, nh=(tid&1)*32;
    const float* wr = Wg + k0*64 + nh;
    #pragma unroll
    for(int q=0;q<8;q++){
      float4 u=ld4(wr+q*4);
      float uu[4]={u.x,u.y,u.z,u.w};
      #pragma unroll
      for(int j=0;j<4;j++){
        int n=nh+q*4+j;
        h16 hh,ll; split2(uu[j],hh,ll);
        int off=(n*256+k0*2)^((n&7)<<4);
        *(h16*)((char*)Wph+off)=hh;
        *(h16*)((char*)Wpl+off)=ll;
      }
    }
  }
  float tv=(tid<128)? Xb[tid*129]:0.f;
  float tr=block_sum(tv,(float*)(lds+32768),tid);   // trace; also syncs staging
  float al=alphaP[0];
  float f1=1.f/(tr+1e-4f);
  float scl=(1.f-al)*f1;
  float shift=al*(tr*f1)*(1.f/128.f);
  // ---- phase 1a: T = X W (A-frags streamed from global, split on the fly)
  f32x4 aM[2][4], aC[2][4];
  const f32x4 vz={0.f,0.f,0.f,0.f};
  #pragma unroll
  for(int rt=0;rt<2;rt++)
    #pragma unroll
    for(int ct=0;ct<4;ct++){ aM[rt][ct]=vz; aC[rt][ct]=vz; }
  int mb=wv*32;
  for(int ks=0;ks<4;ks++){
    h16x8 xah[2], xal[2];
    #pragma unroll
    for(int rt=0;rt<2;rt++){
      const float* px=Xb+(size_t)(mb+16*rt+lr)*128+ks*32+lg*8;
      float4 u0=ld4(px), u1=ld4(px+4);
      float uv[8]={u0.x,u0.y,u0.z,u0.w,u1.x,u1.y,u1.z,u1.w};
      #pragma unroll
      for(int e=0;e<8;e++){ h16 hh,ll; split2(uv[e],hh,ll); xah[rt][e]=hh; xal[rt][e]=ll; }
    }
    #pragma unroll
    for(int ct=0;ct<4;ct++){
      h16x8 bh=frag_ld2(Wph,ct*16+lr,ks,lg);
      h16x8 bl=frag_ld2(Wpl,ct*16+lr,ks,lg);
      #pragma unroll
      for(int rt=0;rt<2;rt++){
        aM[rt][ct]=__builtin_amdgcn_mfma_f32_16x16x32_f16(xah[rt],bh,aM[rt][ct],0,0,0);
        aC[rt][ct]=__builtin_amdgcn_mfma_f32_16x16x32_f16(xal[rt],bh,aC[rt][ct],0,0,0);
        aC[rt][ct]=__builtin_amdgcn_mfma_f32_16x16x32_f16(xah[rt],bl,aC[rt][ct],0,0,0);
      }
    }
  }
  __syncthreads();                 // trace reduce done before T-store reuse
  #pragma unroll
  for(int rt=0;rt<2;rt++){    // store T planes [n][k=m]
    int i0=mb+16*rt+lg*4;
    #pragma unroll
    for(int ct=0;ct<4;ct++){
      int j=ct*16+lr;
      h16x4 h4,l4;
      #pragma unroll
      for(int r=0;r<4;r++){
        float x=aM[rt][ct][r]+aC[rt][ct][r]*SPLIT_R;
        h16 hh,ll; split2(x,hh,ll); h4[r]=hh; l4[r]=ll;
      }
      int off=(j*256+i0*2)^((j&7)<<4);
      *(h16x4*)((char*)Tph+off)=h4;
      *(h16x4*)((char*)Tpl+off)=l4;
    }
  }
  __syncthreads();
  // ---- phase 1b: M0 = W^T T
  f32x4 sM[2][2], sC[2][2];
  #pragma unroll
  for(int rt=0;rt<2;rt++){ sM[rt][0]=vz; sM[rt][1]=vz; sC[rt][0]=vz; sC[rt][1]=vz; }
  int rb=(wv&1)*32, cb=(wv>>1)*32;
  for(int ks=0;ks<4;ks++){
    h16x8 ah2[2], al2[2];
    #pragma unroll
    for(int rt=0;rt<2;rt++){
      ah2[rt]=frag_ld2(Wph,rb+16*rt+lr,ks,lg);
      al2[rt]=frag_ld2(Wpl,rb+16*rt+lr,ks,lg);
    }
    #pragma unroll
    for(int ct=0;ct<2;ct++){
      h16x8 bh=frag_ld2(Tph,cb+16*ct+lr,ks,lg);
      h16x8 bl=frag_ld2(Tpl,cb+16*ct+lr,ks,lg);
      #pragma unroll
      for(int rt=0;rt<2;rt++){
        sM[rt][ct]=__builtin_amdgcn_mfma_f32_16x16x32_f16(ah2[rt],bh,sM[rt][ct],0,0,0);
        sC[rt][ct]=__builtin_amdgcn_mfma_f32_16x16x32_f16(al2[rt],bh,sC[rt][ct],0,0,0);
        sC[rt][ct]=__builtin_amdgcn_mfma_f32_16x16x32_f16(ah2[rt],bl,sC[rt][ct],0,0,0);
      }
    }
  }
  f32x4 accS[2][2];
  #pragma unroll
  for(int rt=0;rt<2;rt++)
    #pragma unroll
    for(int ct=0;ct<2;ct++) accS[rt][ct]=sM[rt][ct]+sC[rt][ct]*SPLIT_R;
  __syncthreads();                 // all Wp/Tp reads done before slot reuse
  st_gl(S1g+(size_t)b*4096, accS, lane,wv, scl, shift);   // S1 = scl*M0+shift*I
  h16* Ah=(h16*)lds;          h16* Al=Ah+4096;
  h16* Xh=(h16*)(lds+16384);  h16* Xl=Xh+4096;
  h16* Th=(h16*)(lds+32768);  h16* Tl=Th+4096;
  float* red=(float*)(lds+49152);
  stS(Ah,Al,accS,dI,lane,wv, scl, shift + C1);            // A = S1 + C1*I
  __syncthreads();
  f32x4 aL[2][2];
  h16* parkh=(h16*)(R2+(size_t)b*4096);
  logm4<4,15,1>(Ah,Al,Xh,Xl,Th,Tl,parkh,red,dI, C1, tid,lane,wv, aL);
  __syncthreads();
  st_gl(R2+(size_t)b*4096, aL, lane,wv, 2.f, LNC1);       // L1 = 2 P R + ln(c) I
}

// column-mean over batch (unchanged)
__global__ __launch_bounds__(256) void kRed(const float* __restrict__ R2, float* outM, float scale){
  __shared__ float red[256];
  int tid=threadIdx.x; int ee=tid&31; int sl=tid>>5;
  int e0 = blockIdx.x*32 + ee;
  float s=0.f;
  for(int j=0;j<256;j++) s += R2[(size_t)(sl+8*j)*4096 + e0];
  red[tid]=s; __syncthreads();
  if (sl<4) red[tid]+=red[tid+128];
  __syncthreads();
  if (sl<2) red[tid]+=red[tid+64];
  __syncthreads();
  if (sl==0) outM[e0] = (red[tid]+red[tid+32])*scale;
}

// G0^{+-1/2} = exp(+-Lbar/2); Bs = sqrt(sym(bn_bias))
__global__ __launch_bounds__(256) void kB(const float* Lbar, const float* biasP,
     float* Gi0, float* Gs0, float* Bs){
  __shared__ __align__(16) char lds[50176];
  int tid=threadIdx.x, lane=tid&63, wv=tid>>6;
  DECL_DI(dI);
  h16* s0h=(h16*)lds;          h16* s0l=s0h+4096;
  h16* s1h=(h16*)(lds+16384);  h16* s1l=s1h+4096;
  h16* s2h=(h16*)(lds+32768);  h16* s2l=s2h+4096;
  float* red=(float*)(lds+49152);
  float tr = block_sum((tid<64)? Lbar[tid*65]:0.f, red, tid);
  float cb_ = tr*(1.f/64.f);
  fill_gl(s0h,s0l, Lbar, 0.5f, -cb_, tid);                // +D/2
  __syncthreads();
  exp4(s0h,s0l,s1h,s1l,s2h,s2l, dI, 1.f, tid,lane,wv);    // exp(D/2) in s0
  plane_out(s0h,s0l, Gs0, expf(0.5f*cb_), tid);
  __syncthreads();
  fill_gl(s0h,s0l, Lbar, -0.5f, -cb_, tid);               // -D/2
  __syncthreads();
  exp4(s0h,s0l,s1h,s1l,s2h,s2l, dI, 1.f, tid,lane,wv);    // exp(-D/2) in s0
  plane_out(s0h,s0l, Gi0, expf(-0.5f*cb_), tid);
  __syncthreads();
  float tb = block_sum((tid<64)? biasP[tid*65]:0.f, red, tid);
  float itb=1.f/tb;
  { // Y = sym(bias)/tb -> s0
    int r=tid>>2;
    #pragma unroll
    for(int q=0;q<4;q++){
      int c4=(tid&3)*16+q*4;
      float4 v=ld4(biasP + r*64 + c4);
      float vv[4]={v.x,v.y,v.z,v.w};
      h16x4 h4,l4;
      #pragma unroll
      for(int j=0;j<4;j++){
        float x = 0.5f*(vv[j] + biasP[(c4+j)*64 + r]) * itb;
        h16 hh,ll; split2(x,hh,ll); h4[j]=hh; l4[j]=ll;
      }
      h4_st(s0h,r,c4,h4); h4_st(s0l,r,c4,l4);
    }
  }
  __syncthreads();
  ns_sqrt3(s0h,s0l,s1h,s1l,s2h,s2l, dI, tid,lane,wv);
  plane_out(s0h,s0l, Bs, sqrtf(tb), tid);
}

// Karcher-step log: M = Gi S1 Gi ; L = logm(M) -> R2 ; optional v accumulation
__global__ __launch_bounds__(256,3) void kC(const float* __restrict__ S1g, const float* GiP,
     float* R2, float* vpart, int doV){
  __shared__ __align__(16) char lds[50176];
  int tid=threadIdx.x, b=blockIdx.x, lane=tid&63, wv=tid>>6;
  DECL_DI(dI);
  h16* s0h=(h16*)lds;          h16* s0l=s0h+4096;
  h16* s1h=(h16*)(lds+16384);  h16* s1l=s1h+4096;
  h16* s2h=(h16*)(lds+32768);  h16* s2l=s2h+4096;
  float* red=(float*)(lds+49152);
  fill_gl(s0h,s0l, S1g+(size_t)b*4096, 1.f,0.f, tid);
  fill_gl(s1h,s1l, GiP, 1.f,0.f, tid);
  __syncthreads();
  f32x4 acc[2][2];
  mmT<1,1,0>(s0h,s0l,s1h,s1l,0,acc,lane,wv);              // S1 Gi
  stS(s2h,s2l,acc,dI,lane,wv,1.f,0.f); __syncthreads();
  mmT<1,1,0>(s1h,s1l,s2h,s2l,0,acc,lane,wv);              // M = Gi S1 Gi
  stS(s0h,s0l,acc,dI,lane,wv,1.f,1.f); __syncthreads();   // A = M + I
  f32x4 aL[2][2];
  h16* parkh=(h16*)(R2+(size_t)b*4096);
  logm4<8,30,2>(s0h,s0l,s1h,s1l,s2h,s2l,parkh,red,dI, 1.f, tid,lane,wv, aL);
  __syncthreads();
  st_gl(R2+(size_t)b*4096, aL, lane,wv, 2.f, 0.f);
  if (doV){
    float s=0.f;
    #pragma unroll
    for(int rt=0;rt<2;rt++)
      #pragma unroll
      for(int ct=0;ct<2;ct++)
        #pragma unroll
        for(int r=0;r<4;r++){ float lv=2.f*aL[rt][ct][r]; s=fmaf(lv,lv,s); }
    __syncthreads();
    s = block_sum(s, red, tid);
    if (tid==0) atomicAdd(vpart + (b&31), s);
  }
}

// G_new = Gs exp(Ebar) Gs ; then G_new^{+-1/2}
__global__ __launch_bounds__(256) void kD(const float* Ebar, const float* GsP,
     float* GsN, float* GiN){
  __shared__ __align__(16) char lds[50176];
  int tid=threadIdx.x, lane=tid&63, wv=tid>>6;
  DECL_DI(dI);
  h16* s0h=(h16*)lds;          h16* s0l=s0h+4096;
  h16* s1h=(h16*)(lds+16384);  h16* s1l=s1h+4096;
  h16* s2h=(h16*)(lds+32768);  h16* s2l=s2h+4096;
  float* red=(float*)(lds+49152);
  fill_gl(s0h,s0l, Ebar, 1.f,0.f, tid); __syncthreads();
  exp4(s0h,s0l,s1h,s1l,s2h,s2l, dI, 1.f, tid,lane,wv);    // E in s0
  fill_gl(s1h,s1l, GsP, 1.f,0.f, tid);                    // s1 dead after exp4
  __syncthreads();
  f32x4 acc[2][2];
  mmT<1,1,0>(s0h,s0l,s1h,s1l,0,acc,lane,wv);              // E Gs -> s2
  stS(s2h,s2l,acc,dI,lane,wv,1.f,0.f); __syncthreads();
  mmT<1,1,0>(s1h,s1l,s2h,s2l,0,acc,lane,wv);              // G = Gs (E Gs)
  float tv=0.f;
  #pragma unroll
  for(int rt=0;rt<2;rt++)
    #pragma unroll
    for(int ct=0;ct<2;ct++)
      #pragma unroll
      for(int r=0;r<4;r++) tv += acc[rt][ct][r]*dI[rt][ct][r];
  float t = block_sum(tv, red, tid);
  stS(s0h,s0l,acc,dI,lane,wv,1.f/t,0.f); __syncthreads(); // Y = G/t -> s0
  ns_sqrt3(s0h,s0l,s1h,s1l,s2h,s2l, dI, tid,lane,wv);
  float st_=sqrtf(t), ist=1.f/st_;
  plane_out(s0h,s0l, GsN, st_, tid);
  plane_out(s1h,s1l, GiN, ist, tid);
}

__global__ void kF2(const float* vpart, const float* gammaP, float* sOut){
  if (threadIdx.x==0 && blockIdx.x==0){
    float v=0.f;
    for(int i=0;i<32;i++) v+=vpart[i];
    v *= (1.f/2048.f);
    sOut[0] = gammaP[0] / sqrtf(v + 1e-5f);
  }
}

// Y=exp(s Lt); Z=Bs Y Bs; Lg=logm(Z); out = triu(Lg)*coef @ Wc^T + bc
__global__ __launch_bounds__(256,3) void kG(float* R2, const float* BsP, const float* sP,
     const float* __restrict__ WcP, const float* bcP, float* outP){
  __shared__ __align__(16) char lds[50176];
  int tid=threadIdx.x, b=blockIdx.x, lane=tid&63, wv=tid>>6;
  DECL_DI(dI);
  h16* s0h=(h16*)lds;          h16* s0l=s0h+4096;
  h16* s1h=(h16*)(lds+16384);  h16* s1l=s1h+4096;
  h16* s2h=(h16*)(lds+32768);  h16* s2l=s2h+4096;
  float* red=(float*)(lds+49152);
  fill_gl(s0h,s0l, R2+(size_t)b*4096, 1.f,0.f, tid); __syncthreads();  // Lt
  float s = sP[0];
  exp4(s0h,s0l,s1h,s1l,s2h,s2l, dI, s, tid,lane,wv);      // Y in s0
  fill_gl(s1h,s1l, BsP, 1.f,0.f, tid);                    // s1 dead after exp4
  __syncthreads();
  f32x4 acc[2][2];
  mmT<1,1,0>(s0h,s0l,s1h,s1l,0,acc,lane,wv);              // Y Bs -> s2
  stS(s2h,s2l,acc,dI,lane,wv,1.f,0.f); __syncthreads();
  mmT<1,1,0>(s1h,s1l,s2h,s2l,0,acc,lane,wv);              // Z = Bs Y Bs
  stS(s0h,s0l,acc,dI,lane,wv,1.f,1.f); __syncthreads();   // A = Z + I -> s0
  f32x4 aL[2][2];
  h16* parkh=(h16*)(R2+(size_t)b*4096);
  logm4<4,15,2>(s0h,s0l,s1h,s1l,s2h,s2l,parkh,red,dI, 1.f, tid,lane,wv, aL);
  // epilogue: triu(2*P*R) * coef @ Wc^T
  float o0=0,o1=0,o2=0,o3=0;
  {
    int lr=lane&15, lq=lane>>4, rb=(wv&1)*32, cb=(wv>>1)*32;
    #pragma unroll
    for(int rt=0;rt<2;rt++)
      #pragma unroll
      for(int ct=0;ct<2;ct++)
        #pragma unroll
        for(int r=0;r<4;r++){
          int i=rb+16*rt+lq*4+r, j=cb+16*ct+lr;
          float lg2=2.f*aL[rt][ct][r];
          int a=(i<j)? i:j, bb=(i<j)? j:i;
          int tri = a*64 - ((a*(a-1))>>1) + (bb-a);
          float w = (i==j)? lg2 : lg2*0.70710678118654752f;
          o0=fmaf(w, WcP[tri],      o0);
          o1=fmaf(w, WcP[2080+tri], o1);
          o2=fmaf(w, WcP[4160+tri], o2);
          o3=fmaf(w, WcP[6240+tri], o3);
        }
  }
  __syncthreads();
  float* redv=(float*)lds;
  float4 pk; pk.x=o0; pk.y=o1; pk.z=o2; pk.w=o3;
  st4(redv+4*tid, pk); __syncthreads();
  for(int off=128; off>0; off>>=1){
    if (tid<off){
      float4 x=ld4(redv+4*tid), y=ld4(redv+4*(tid+off));
      x.x+=y.x; x.y+=y.y; x.z+=y.z; x.w+=y.w;
      st4(redv+4*tid, x);
    }
    __syncthreads();
  }
  if (tid==0){
    outP[b*4+0]=redv[0]+bcP[0];
    outP[b*4+1]=redv[1]+bcP[1];
    outP[b*4+2]=redv[2]+bcP[2];
    outP[b*4+3]=redv[3]+bcP[3];
  }
}

extern "C" void kernel_launch(void* const* d_in, const int* in_sizes, int n_in,
                              void* d_out, int out_size, void* d_ws, size_t ws_size,
                              hipStream_t stream){
  const float* X     = (const float*)d_in[0];
  const float* alpha = (const float*)d_in[1];
  const float* W     = (const float*)d_in[2];
  const float* gamma = (const float*)d_in[3];
  const float* bias  = (const float*)d_in[4];
  const float* Wc    = (const float*)d_in[5];
  const float* bc    = (const float*)d_in[6];
  float* ws = (float*)d_ws;
  float* S1 = ws + WS_S1;
  float* R2 = ws + WS_R2;
  float* sm = ws + WS_SM;

  hipMemsetAsync(sm + SM_VPART, 0, 33*sizeof(float), stream);

  kA  <<<2048,256,0,stream>>>(X, alpha, W, S1, R2);
  kRed<<<128, 256,0,stream>>>(R2, sm+SM_LBAR, 1.f/2048.f);
  kB  <<<1,   256,0,stream>>>(sm+SM_LBAR, bias, sm+SM_GI0, sm+SM_GS0, sm+SM_BS);
  kC  <<<2048,256,0,stream>>>(S1, sm+SM_GI0, R2, nullptr, 0);
  kRed<<<128, 256,0,stream>>>(R2, sm+SM_EBAR1, 1.f/2048.f);
  kD  <<<1,   256,0,stream>>>(sm+SM_EBAR1, sm+SM_GS0, sm+SM_GS1, sm+SM_GI1);
  kC  <<<2048,256,0,stream>>>(S1, sm+SM_GI1, R2, nullptr, 0);
  kRed<<<128, 256,0,stream>>>(R2, sm+SM_EBAR2, 1.f/2048.f);
  kD  <<<1,   256,0,stream>>>(sm+SM_EBAR2, sm+SM_GS1, sm+SM_GS2, sm+SM_GI2);
  kC  <<<2048,256,0,stream>>>(S1, sm+SM_GI2, R2, sm+SM_VPART, 1);
  kF2 <<<1,1,0,stream>>>(sm+SM_VPART, gamma, sm+SM_S);
  kG  <<<2048,256,0,stream>>>(R2, sm+SM_BS, sm+SM_S, Wc, bc, (float*)d_out);
}

// Round 5
// 774.942 us; speedup vs baseline: 5.4696x; 1.0050x over previous
//
#include <hip/hip_runtime.h>
#include <math.h>

// ============================================================================
// SPDNet forward, eig-free — v5:
//  * kA BiMap restructured to two K-halves: LDS 64->49KB => 3 blocks/CU
//  * poly loops (logm Horner, exp Horner) cache W right-operand hi-frags in
//    registers (loop-invariant): 4 fewer LDS reads per iteration
//  * s_setprio(1) around MFMA clusters (3 indep blocks/CU at distinct phases)
//  * chunk-4 Paterson-Stockmeyer logm, single-barrier phases, split-f16 MFMA
// Split scheme: v = hi + lo/4096 (f16,f16), 3 MFMAs = fp32-class accuracy.
// Planes store TRANSPOSE of semantic matrix; mm(L,R) = L^T R (left ops symm).
// ============================================================================

#define NSC_IT  12
#define C1      0.0038729833f
#define LNC1    (-5.553730f)
#define SPLIT_S 4096.f
#define SPLIT_R (1.f/4096.f)

typedef _Float16 h16;
typedef _Float16 h16x8 __attribute__((ext_vector_type(8)));
typedef _Float16 h16x4 __attribute__((ext_vector_type(4)));
typedef float    f32x4 __attribute__((ext_vector_type(4)));

// ws layout (floats)
#define WS_S1   ((size_t)0)
#define WS_R2   ((size_t)8388608)
#define WS_SM   ((size_t)16777216)
#define SM_LBAR  0
#define SM_EBAR1 4096
#define SM_EBAR2 8192
#define SM_GI0   12288
#define SM_GS0   16384
#define SM_GI1   20480
#define SM_GS1   24576
#define SM_GI2   28672
#define SM_GS2   32768
#define SM_BS    36864
#define SM_VPART 40960
#define SM_S     40992

__device__ __forceinline__ float4 ld4(const float* p){ return *(const float4*)p; }
__device__ __forceinline__ void  st4(float* p, float4 v){ *(float4*)p = v; }

// ---------------- split-f16 plane helpers (64x64, 128B row stride) ---------
__device__ __forceinline__ int eoff(int r, int c){ return (r*128 + c*2) ^ ((r&7)<<4); }

__device__ __forceinline__ h16x8 frag_ld(const h16* p, int row, int ks, int lg){
  int off = (row*128 + ks*64 + lg*16) ^ ((row&7)<<4);
  return *(const h16x8*)((const char*)p + off);
}
// 64x128 plane (256B row stride), ks in 0..3
__device__ __forceinline__ h16x8 frag_ld2(const h16* p, int row, int ks, int lg){
  int off = (row*256 + ks*64 + lg*16) ^ ((row&7)<<4);
  return *(const h16x8*)((const char*)p + off);
}
__device__ __forceinline__ h16x4 h4_ld(const h16* p, int r, int c4){
  return *(const h16x4*)((const char*)p + eoff(r,c4));
}
__device__ __forceinline__ void h4_st(h16* p, int r, int c4, h16x4 v){
  *(h16x4*)((char*)p + eoff(r,c4)) = v;
}
__device__ __forceinline__ void split2(float v, h16& h, h16& l){
  h16 hh = (h16)v;
  h = hh;
  l = (h16)((v - (float)hh) * SPLIT_S);
}
__device__ __forceinline__ float join2(h16 h, h16 l){
  return (float)h + (float)l * SPLIT_R;
}

// ---------------- MFMA 64x64x64: D = L^T * R ------------------------------
// AS/BS: whether left/right lo-planes participate. GP: B from global (linear).
template<int AS,int BS,int GP>
__device__ __forceinline__ void mmT(const h16* Lh,const h16* Ll,
                                    const h16* Rh,const h16* Rl,const h16* gR,
                                    f32x4 acc[2][2], int lane,int wv){
  const int lr=lane&15, lg=lane>>4;
  const int rb=(wv&1)*32, cb=(wv>>1)*32;
  h16x8 ah[2][2], al[2][2];
  #pragma unroll
  for(int rt=0;rt<2;rt++){
    #pragma unroll
    for(int ks=0;ks<2;ks++){
      ah[rt][ks]=frag_ld(Lh, rb+16*rt+lr, ks, lg);
      if(AS) al[rt][ks]=frag_ld(Ll, rb+16*rt+lr, ks, lg);
    }
  }
  f32x4 aM[2][2], aC[2][2];
  const f32x4 vz={0.f,0.f,0.f,0.f};
  #pragma unroll
  for(int rt=0;rt<2;rt++){ aM[rt][0]=vz; aM[rt][1]=vz; aC[rt][0]=vz; aC[rt][1]=vz; }
  __builtin_amdgcn_s_setprio(1);
  #pragma unroll
  for(int ct=0;ct<2;ct++){
    #pragma unroll
    for(int ks=0;ks<2;ks++){
      h16x8 bh, bl;
      if(GP){
        const h16* g = gR + (cb+16*ct+lr)*64 + ks*32 + lg*8;
        bh = *(const h16x8*)g;
        if(BS) bl = *(const h16x8*)(g+4096);
      }else{
        bh = frag_ld(Rh, cb+16*ct+lr, ks, lg);
        if(BS) bl = frag_ld(Rl, cb+16*ct+lr, ks, lg);
      }
      #pragma unroll
      for(int rt=0;rt<2;rt++){
        aM[rt][ct]=__builtin_amdgcn_mfma_f32_16x16x32_f16(ah[rt][ks],bh,aM[rt][ct],0,0,0);
        if(AS) aC[rt][ct]=__builtin_amdgcn_mfma_f32_16x16x32_f16(al[rt][ks],bh,aC[rt][ct],0,0,0);
        if(BS) aC[rt][ct]=__builtin_amdgcn_mfma_f32_16x16x32_f16(ah[rt][ks],bl,aC[rt][ct],0,0,0);
      }
    }
  }
  __builtin_amdgcn_s_setprio(0);
  #pragma unroll
  for(int rt=0;rt<2;rt++)
    #pragma unroll
    for(int ct=0;ct<2;ct++)
      acc[rt][ct] = (AS||BS) ? (aM[rt][ct] + aC[rt][ct]*SPLIT_R) : aM[rt][ct];
}

// preload this wave's B-side hi fragments of the plane at Rh (loop-invariant W)
__device__ __forceinline__ void preB(const h16* Rh, h16x8 wb[2][2], int lane,int wv){
  const int lr=lane&15, lg=lane>>4, cb=(wv>>1)*32;
  #pragma unroll
  for(int ct=0;ct<2;ct++)
    #pragma unroll
    for(int ks=0;ks<2;ks++)
      wb[ct][ks]=frag_ld(Rh, cb+16*ct+lr, ks, lg);
}

// split mm with B-hi from registers, B-lo from LDS
__device__ __forceinline__ void mmT_wb(const h16* Lh,const h16* Ll,
                                       const h16x8 wb[2][2], const h16* Rl,
                                       f32x4 acc[2][2], int lane,int wv){
  const int lr=lane&15, lg=lane>>4;
  const int rb=(wv&1)*32, cb=(wv>>1)*32;
  h16x8 ah[2][2], al[2][2];
  #pragma unroll
  for(int rt=0;rt<2;rt++){
    #pragma unroll
    for(int ks=0;ks<2;ks++){
      ah[rt][ks]=frag_ld(Lh, rb+16*rt+lr, ks, lg);
      al[rt][ks]=frag_ld(Ll, rb+16*rt+lr, ks, lg);
    }
  }
  f32x4 aM[2][2], aC[2][2];
  const f32x4 vz={0.f,0.f,0.f,0.f};
  #pragma unroll
  for(int rt=0;rt<2;rt++){ aM[rt][0]=vz; aM[rt][1]=vz; aC[rt][0]=vz; aC[rt][1]=vz; }
  __builtin_amdgcn_s_setprio(1);
  #pragma unroll
  for(int ct=0;ct<2;ct++){
    #pragma unroll
    for(int ks=0;ks<2;ks++){
      h16x8 bl=frag_ld(Rl, cb+16*ct+lr, ks, lg);
      #pragma unroll
      for(int rt=0;rt<2;rt++){
        aM[rt][ct]=__builtin_amdgcn_mfma_f32_16x16x32_f16(ah[rt][ks],wb[ct][ks],aM[rt][ct],0,0,0);
        aC[rt][ct]=__builtin_amdgcn_mfma_f32_16x16x32_f16(al[rt][ks],wb[ct][ks],aC[rt][ct],0,0,0);
        aC[rt][ct]=__builtin_amdgcn_mfma_f32_16x16x32_f16(ah[rt][ks],bl,aC[rt][ct],0,0,0);
      }
    }
  }
  __builtin_amdgcn_s_setprio(0);
  #pragma unroll
  for(int rt=0;rt<2;rt++)
    #pragma unroll
    for(int ct=0;ct<2;ct++)
      acc[rt][ct] = aM[rt][ct] + aC[rt][ct]*SPLIT_R;
}

// split store to plane (transposed): x = acc*scale + dadd*dI
__device__ __forceinline__ void stS(h16* Dh,h16* Dl,const f32x4 acc[2][2],
                                    const float (*dI)[2][4],
                                    int lane,int wv,float scale,float dadd){
  const int lr=lane&15, lg=lane>>4, rb=(wv&1)*32, cb=(wv>>1)*32;
  #pragma unroll
  for(int rt=0;rt<2;rt++){
    int i0=rb+16*rt+lg*4;
    #pragma unroll
    for(int ct=0;ct<2;ct++){
      int j=cb+16*ct+lr;
      h16x4 h4,l4;
      #pragma unroll
      for(int r=0;r<4;r++){
        float x=fmaf(acc[rt][ct][r],scale, dadd*dI[rt][ct][r]);
        h16 hh,ll; split2(x,hh,ll); h4[r]=hh; l4[r]=ll;
      }
      int off=(j*128+i0*2)^((j&7)<<4);
      *(h16x4*)((char*)Dh+off)=h4;
      *(h16x4*)((char*)Dl+off)=l4;
    }
  }
}
// hi-only store
__device__ __forceinline__ void stH(h16* Dh,const f32x4 acc[2][2],
                                    const float (*dI)[2][4],
                                    int lane,int wv,float scale,float dadd){
  const int lr=lane&15, lg=lane>>4, rb=(wv&1)*32, cb=(wv>>1)*32;
  #pragma unroll
  for(int rt=0;rt<2;rt++){
    int i0=rb+16*rt+lg*4;
    #pragma unroll
    for(int ct=0;ct<2;ct++){
      int j=cb+16*ct+lr;
      h16x4 h4;
      #pragma unroll
      for(int r=0;r<4;r++){
        float x=fmaf(acc[rt][ct][r],scale, dadd*dI[rt][ct][r]);
        h4[r]=(h16)x;
      }
      int off=(j*128+i0*2)^((j&7)<<4);
      *(h16x4*)((char*)Dh+off)=h4;
    }
  }
}

// store D to global f32 (outputs symmetric; transpose ok)
__device__ __forceinline__ void st_gl(float* G, const f32x4 acc[2][2],
                                      int lane,int wv,float scale,float dadd){
  const int lr=lane&15, lg=lane>>4, rb=(wv&1)*32, cb=(wv>>1)*32;
  #pragma unroll
  for(int rt=0;rt<2;rt++){
    int i0=rb+16*rt+lg*4;
    #pragma unroll
    for(int ct=0;ct<2;ct++){
      int j=cb+16*ct+lr;
      float4 v; float* vf=(float*)&v;
      #pragma unroll
      for(int r=0;r<4;r++){
        float x=acc[rt][ct][r]*scale;
        if (i0+r==j) x += dadd;
        vf[r]=x;
      }
      st4(G + j*64 + i0, v);
    }
  }
}

// park D to global split (hi at gh[0:4096], lo at gh[4096:8192]), linear
__device__ __forceinline__ void st_park(h16* gh, const f32x4 acc[2][2], int lane,int wv){
  const int lr=lane&15, lg=lane>>4, rb=(wv&1)*32, cb=(wv>>1)*32;
  #pragma unroll
  for(int rt=0;rt<2;rt++){
    int i0=rb+16*rt+lg*4;
    #pragma unroll
    for(int ct=0;ct<2;ct++){
      int j=cb+16*ct+lr;
      h16x4 h4,l4;
      #pragma unroll
      for(int r=0;r<4;r++){ h16 hh,ll; split2(acc[rt][ct][r],hh,ll); h4[r]=hh; l4[r]=ll; }
      *(h16x4*)(gh + j*64 + i0) = h4;
      *(h16x4*)(gh + 4096 + j*64 + i0) = l4;
    }
  }
}

// snapshot plane values at this thread's D positions into registers
__device__ __forceinline__ void snap(const h16* Ph,const h16* Pl,float (*v)[2][4],
                                     int lane,int wv){
  const int lr=lane&15, lg=lane>>4, rb=(wv&1)*32, cb=(wv>>1)*32;
  #pragma unroll
  for(int rt=0;rt<2;rt++){
    int i0=rb+16*rt+lg*4;
    #pragma unroll
    for(int ct=0;ct<2;ct++){
      int j=cb+16*ct+lr;
      h16x4 h=h4_ld(Ph,j,i0), l=h4_ld(Pl,j,i0);
      #pragma unroll
      for(int r=0;r<4;r++) v[rt][ct][r]=join2(h[r],l[r]);
    }
  }
}

// snapshot acc into registers (same D positions, no LDS traffic)
__device__ __forceinline__ void snapa(float (*v)[2][4], const f32x4 acc[2][2]){
  #pragma unroll
  for(int rt=0;rt<2;rt++)
    #pragma unroll
    for(int ct=0;ct<2;ct++)
      #pragma unroll
      for(int r=0;r<4;r++) v[rt][ct][r]=acc[rt][ct][r];
}

__device__ __forceinline__ void addK4(f32x4 acc[2][2], const float (*dI)[2][4],
    const float (*sv)[2][4], const float (*s2v)[2][4], const float (*s3v)[2][4],
    float a0,float a1,float a2,float a3){
  #pragma unroll
  for(int rt=0;rt<2;rt++)
    #pragma unroll
    for(int ct=0;ct<2;ct++)
      #pragma unroll
      for(int r=0;r<4;r++)
        acc[rt][ct][r] += a0*dI[rt][ct][r] + a1*sv[rt][ct][r]
                        + a2*s2v[rt][ct][r] + a3*s3v[rt][ct][r];
}

__device__ __forceinline__ void addK3(f32x4 acc[2][2], const float (*dI)[2][4],
    const float (*lv)[2][4], const float (*l2v)[2][4],
    float a0,float a1,float a2){
  #pragma unroll
  for(int rt=0;rt<2;rt++)
    #pragma unroll
    for(int ct=0;ct<2;ct++)
      #pragma unroll
      for(int r=0;r<4;r++)
        acc[rt][ct][r] += a0*dI[rt][ct][r] + a1*lv[rt][ct][r] + a2*l2v[rt][ct][r];
}

// fill planes from global f32 symmetric: x = (v + dshift_on_diag)*scale
__device__ __forceinline__ void fill_gl(h16* Ph, h16* Pl, const float* g,
                                        float scale, float dshift, int tid){
  int r = tid>>2;
  #pragma unroll
  for(int q=0;q<4;q++){
    int c4 = (tid&3)*16 + q*4;
    float4 v = ld4(g + r*64 + c4);
    float vv[4]={v.x,v.y,v.z,v.w};
    h16x4 h4,l4;
    #pragma unroll
    for(int j=0;j<4;j++){
      float x = vv[j];
      if (c4+j == r) x += dshift;
      x *= scale;
      h16 hh,ll; split2(x,hh,ll); h4[j]=hh; l4[j]=ll;
    }
    h4_st(Ph,r,c4,h4); h4_st(Pl,r,c4,l4);
  }
}

__device__ __forceinline__ void plane_out(const h16* Ph, const h16* Pl, float* g,
                                          float scale, int tid){
  int r=tid>>2;
  #pragma unroll
  for(int q=0;q<4;q++){
    int c4=(tid&3)*16+q*4;
    h16x4 h4=h4_ld(Ph,r,c4), l4=h4_ld(Pl,r,c4);
    float4 v;
    v.x=join2(h4[0],l4[0])*scale;
    v.y=join2(h4[1],l4[1])*scale;
    v.z=join2(h4[2],l4[2])*scale;
    v.w=join2(h4[3],l4[3])*scale;
    st4(g + r*64 + c4, v);
  }
}

__device__ __forceinline__ void diag_add(h16* Ph, h16* Pl, float add, int tid){
  if (tid<64){
    int off = (tid*128 + tid*2) ^ ((tid&7)<<4);
    h16* ph = (h16*)((char*)Ph + off);
    h16* pl = (h16*)((char*)Pl + off);
    float v = join2(*ph,*pl) + add;
    h16 hh,ll; split2(v,hh,ll);
    *ph=hh; *pl=ll;
  }
}

__device__ float block_sum(float v, float* red, int tid){
  red[tid]=v; __syncthreads();
  for(int off=128; off>0; off>>=1){
    if (tid<off) red[tid]+=red[tid+off];
    __syncthreads();
  }
  float r=red[0]; __syncthreads();
  return r;
}

__device__ __forceinline__ float cfj(int j, int J){
  return (j<=J)? 1.f/(float)(2*j+1) : 0.f;
}

// ---------------- Newton-Schulz inverse: 5 hi ping-pong + NSS split --------
// On exit: X = A^-1 (split); A gets postshift added to its diagonal.
template<int NSS>
__device__ void ns_inv4(h16* Ah,h16* Al,h16* Xh,h16* Xl,h16* Th,h16* Tl,
                        float* red,const float (*dI)[2][4],
                        int tid,int lane,int wv,float lminB,float postshift){
  { // ||A||_inf from hi plane
    int row=tid>>2, seg=tid&3;
    float s=0.f;
    #pragma unroll
    for(int q=0;q<4;q++){
      h16x4 h4 = h4_ld(Ah,row,seg*16+q*4);
      #pragma unroll
      for(int j=0;j<4;j++) s += fabsf((float)h4[j]);
    }
    red[tid]=s*1.001f; __syncthreads();
    if((tid&3)==0) red[tid]=red[tid]+red[tid+1]+red[tid+2]+red[tid+3];
    __syncthreads();
    if(tid==0){ float m=0.f; for(int i=0;i<64;i++) m=fmaxf(m,red[4*i]); red[0]=m; }
    __syncthreads();
  }
  float alpha = 2.f/(lminB + red[0]);
  { // X0 = alpha*I (hi only) into Xh
    int r=tid>>2;
    h16 ahh=(h16)alpha;
    #pragma unroll
    for(int q=0;q<4;q++){
      int c4=(tid&3)*16+q*4;
      h16x4 h4={(h16)0,(h16)0,(h16)0,(h16)0};
      #pragma unroll
      for(int j=0;j<4;j++) if (c4+j==r) h4[j]=ahh;
      h4_st(Xh,r,c4,h4);
    }
  }
  __syncthreads();
  f32x4 acc[2][2];
  #pragma unroll
  for(int it=0;it<5;it++){
    const h16* Xa=(it&1)?Xl:Xh;
    h16* Ta=(it&1)?Tl:Th;
    h16* Xn=(it&1)?Xh:Xl;
    mmT<0,0,0>(Ah,0,Xa,0,0,acc,lane,wv);
    stH(Ta,acc,dI,lane,wv,-1.f,2.f); __syncthreads();   // T = 2I - A X
    mmT<0,0,0>(Xa,0,Ta,0,0,acc,lane,wv);
    stH(Xn,acc,dI,lane,wv,1.f,0.f); __syncthreads();    // X' = X T
  }
  // X-hi now lives in Xl space. Promote with split A (one split NS iter):
  mmT<1,0,0>(Ah,Al,Xl,0,0,acc,lane,wv);
  stS(Th,Tl,acc,dI,lane,wv,-1.f,2.f); __syncthreads();
  mmT<0,1,0>(Xl,0,Th,Tl,0,acc,lane,wv); __syncthreads(); // reads Xl -> barrier
  if(NSS>1){
    stS(Xh,Xl,acc,dI,lane,wv,1.f,0.f); __syncthreads();
    mmT<1,1,0>(Ah,Al,Xh,Xl,0,acc,lane,wv);
    stS(Th,Tl,acc,dI,lane,wv,-1.f,2.f); __syncthreads();
    mmT<1,1,0>(Xh,Xl,Th,Tl,0,acc,lane,wv); __syncthreads();
  }
  stS(Xh,Xl,acc,dI,lane,wv,1.f,0.f);
  diag_add(Ah,Al,postshift,tid);       // fused: A not read in this phase
  __syncthreads();
}

// ---------------- logm, chunk-4 PS. A holds M + cshift*I on entry. --------
// accOut = P*R ; caller: L = 2*accOut + ln(c)*I.
template<int C,int J,int NSS>
__device__ void logm4(h16* Ah,h16* Al,h16* Xh,h16* Xl,h16* Th,h16* Tl,
                      h16* parkh, float* red, const float (*dI)[2][4],
                      float cshift,int tid,int lane,int wv,
                      f32x4 accOut[2][2]){
  ns_inv4<NSS>(Ah,Al,Xh,Xl,Th,Tl,red,dI,tid,lane,wv,cshift,-2.f*cshift);
  f32x4 acc[2][2];
  mmT<1,1,0>(Ah,Al,Xh,Xl,0,acc,lane,wv);               // R = (A-2cI) X
  stS(Th,Tl,acc,dI,lane,wv,1.f,0.f);
  st_park(parkh,acc,lane,wv);
  __syncthreads();
  float sv[2][2][4], s2v[2][2][4], s3v[2][2][4];
  mmT<1,1,0>(Th,Tl,Th,Tl,0,acc,lane,wv);               // S = R^2 -> A
  snapa(sv,acc);
  stS(Ah,Al,acc,dI,lane,wv,1.f,0.f); __syncthreads();
  mmT<1,1,0>(Ah,Al,Ah,Al,0,acc,lane,wv);               // S2 -> X
  snapa(s2v,acc);
  stS(Xh,Xl,acc,dI,lane,wv,1.f,0.f); __syncthreads();
  mmT<1,1,0>(Xh,Xl,Ah,Al,0,acc,lane,wv);               // S3 = S2 S -> T
  snapa(s3v,acc);
  stS(Th,Tl,acc,dI,lane,wv,1.f,0.f); __syncthreads();
  mmT<1,1,0>(Xh,Xl,Xh,Xl,0,acc,lane,wv);               // W = S4 = S2^2 -> A
  stS(Ah,Al,acc,dI,lane,wv,1.f,0.f);
  { // P = K_{C-1} elementwise from snapped powers -> T (same phase as W)
    f32x4 p[2][2];
    float a0=cfj(4*(C-1),J),a1=cfj(4*(C-1)+1,J),a2=cfj(4*(C-1)+2,J),a3=cfj(4*(C-1)+3,J);
    #pragma unroll
    for(int rt=0;rt<2;rt++)
      #pragma unroll
      for(int ct=0;ct<2;ct++)
        #pragma unroll
        for(int r=0;r<4;r++)
          p[rt][ct][r]=a0*dI[rt][ct][r]+a1*sv[rt][ct][r]+a2*s2v[rt][ct][r]+a3*s3v[rt][ct][r];
    stS(Th,Tl,p,dI,lane,wv,1.f,0.f);
  }
  __syncthreads();
  h16x8 wb[2][2];
  preB(Ah,wb,lane,wv);           // W right-frags (hi) cached for the Horner loop
  #pragma unroll
  for(int k=0;k<C-1;k++){        // P = P*W + K_i, ping-pong T<->X
    int i=C-2-k;
    const h16 *Ph=(k&1)?Xh:Th; const h16 *Pl=(k&1)?Xl:Tl;
    h16 *Qh=(k&1)?Th:Xh; h16 *Ql=(k&1)?Tl:Xl;
    mmT_wb(Ph,Pl,wb,Al,acc,lane,wv);
    addK4(acc,dI,sv,s2v,s3v,cfj(4*i,J),cfj(4*i+1,J),cfj(4*i+2,J),cfj(4*i+3,J));
    stS(Qh,Ql,acc,dI,lane,wv,1.f,0.f);
    __syncthreads();
  }
  // C-1 odd (C=4 or 8) -> P ends in X slot
  mmT<1,1,1>(Xh,Xl,(const h16*)0,(const h16*)0,parkh,accOut,lane,wv); // P R
}

// ---------------- exp(s*L): L in slot0 (destroyed), result in slot0 --------
__device__ void exp4(h16* Lh,h16* Ll, h16* Bh,h16* Bl, h16* Wh,h16* Wl,
                     const float (*dI)[2][4], float s, int tid,int lane,int wv){
  float aj[15]; aj[0]=1.f;
  #pragma unroll
  for(int j=1;j<15;j++) aj[j]=aj[j-1]*s/(float)j;
  float lv[2][2][4], l2v[2][2][4];
  snap(Lh,Ll,lv,lane,wv);
  f32x4 acc[2][2];
  mmT<1,1,0>(Lh,Ll,Lh,Ll,0,acc,lane,wv);               // L2 -> B
  snapa(l2v,acc);
  stS(Bh,Bl,acc,dI,lane,wv,1.f,0.f); __syncthreads();
  mmT<1,1,0>(Bh,Bl,Lh,Ll,0,acc,lane,wv);               // W = L3 -> W
  stS(Wh,Wl,acc,dI,lane,wv,1.f,0.f); __syncthreads();
  h16x8 wb[2][2];
  preB(Wh,wb,lane,wv);
  { // P init (deg 12..14) -> L slot (L dead)
    f32x4 p[2][2];
    #pragma unroll
    for(int rt=0;rt<2;rt++)
      #pragma unroll
      for(int ct=0;ct<2;ct++)
        #pragma unroll
        for(int r=0;r<4;r++)
          p[rt][ct][r]=aj[12]*dI[rt][ct][r]+aj[13]*lv[rt][ct][r]+aj[14]*l2v[rt][ct][r];
    stS(Lh,Ll,p,dI,lane,wv,1.f,0.f);
  }
  __syncthreads();
  #pragma unroll
  for(int k=0;k<4;k++){          // ping-pong L<->B ; ends in L
    int i=3-k;
    const h16 *Ph=(k&1)?Bh:Lh; const h16 *Pl=(k&1)?Bl:Ll;
    h16 *Qh=(k&1)?Lh:Bh; h16 *Ql=(k&1)?Ll:Bl;
    mmT_wb(Ph,Pl,wb,Wl,acc,lane,wv);
    addK3(acc,dI,lv,l2v,aj[3*i],aj[3*i+1],aj[3*i+2]);
    stS(Qh,Ql,acc,dI,lane,wv,1.f,0.f);
    __syncthreads();
  }
}

// ---------------- coupled NS sqrt (full split; only 1-block kernels) -------
__device__ void ns_sqrt3(h16* Yh,h16* Yl,h16* Zh,h16* Zl,h16* Th,h16* Tl,
                         const float (*dI)[2][4], int tid,int lane,int wv){
  {
    int r=tid>>2;
    h16 oh,ol; split2(1.f,oh,ol);
    #pragma unroll
    for(int q=0;q<4;q++){
      int c4=(tid&3)*16+q*4;
      h16x4 h4={(h16)0,(h16)0,(h16)0,(h16)0};
      h16x4 l4={(h16)0,(h16)0,(h16)0,(h16)0};
      #pragma unroll
      for(int j=0;j<4;j++) if (c4+j==r){ h4[j]=oh; l4[j]=ol; }
      h4_st(Zh,r,c4,h4); h4_st(Zl,r,c4,l4);
    }
  }
  __syncthreads();
  f32x4 aY[2][2], aZ[2][2];
  for(int it=0; it<NSC_IT; it++){
    mmT<1,1,0>(Zh,Zl,Yh,Yl,0,aY,lane,wv); __syncthreads();
    stS(Th,Tl,aY,dI,lane,wv,-0.5f,1.5f); __syncthreads(); // U = 1.5I - 0.5 Z Y
    mmT<1,1,0>(Yh,Yl,Th,Tl,0,aY,lane,wv);                 // Y U
    mmT<1,1,0>(Th,Tl,Zh,Zl,0,aZ,lane,wv);                 // U Z
    __syncthreads();
    stS(Yh,Yl,aY,dI,lane,wv,1.f,0.f);
    stS(Zh,Zl,aZ,dI,lane,wv,1.f,0.f);
    __syncthreads();
  }
}

#define DECL_DI(dIname) \
  float dIname[2][2][4]; \
  { int rb_=(wv&1)*32, cb_=(wv>>1)*32; \
    _Pragma("unroll") \
    for(int rt=0;rt<2;rt++) \
      _Pragma("unroll") \
      for(int ct=0;ct<2;ct++) \
        _Pragma("unroll") \
        for(int r=0;r<4;r++) \
          dIname[rt][ct][r]=((rb_+16*rt+(lane>>4)*4+r)==(cb_+16*ct+(lane&15)))?1.f:0.f; }

// ---------------- kernels ----------------

// BiMap via split-MFMA (two K-halves, 49KB LDS) + logm(S1) (C=4,J=15)
__global__ __launch_bounds__(256,3) void kA(const float* __restrict__ Xg, const float* alphaP,
    const float* __restrict__ Wg, float* S1g, float* R2){
  __shared__ __align__(16) char lds[50176];
  int tid=threadIdx.x, b=blockIdx.x, lane=tid&63, wv=tid>>6;
  int lr=lane&15, lg=lane>>4;
  DECL_DI(dI);
  const float* Xb = Xg + (size_t)b*16384;
  h16* Wph=(h16*)lds;          h16* Wpl=Wph+8192;    // [64][128] split, 32KB
  h16* Thh=(h16*)(lds+32768);  h16* Thl=Thh+4096;    // [64][64] split, 16KB
  float* red=(float*)(lds+49152);
  { // stage W planes: Wp[n][k] = W[k][n]
    int k0=tid>>1, nh=(tid&1)*32;
    const float* wr = Wg + k0*64 + nh;
    #pragma unroll
    for(int q=0;q<8;q++){
      float4 u=ld4(wr+q*4);
      float uu[4]={u.x,u.y,u.z,u.w};
      #pragma unroll
      for(int j=0;j<4;j++){
        int n=nh+q*4+j;
        h16 hh,ll; split2(uu[j],hh,ll);
        int off=(n*256+k0*2)^((n&7)<<4);
        *(h16*)((char*)Wph+off)=hh;
        *(h16*)((char*)Wpl+off)=ll;
      }
    }
  }
  float tv=(tid<128)? Xb[tid*129]:0.f;
  float tr=block_sum(tv,red,tid);         // trace; also syncs W staging
  float al_=alphaP[0];
  float f1=1.f/(tr+1e-4f);
  float scl=(1.f-al_)*f1;
  float shift=al_*(tr*f1)*(1.f/128.f);
  const int rb=(wv&1)*32, cb=(wv>>1)*32;
  const f32x4 vz={0.f,0.f,0.f,0.f};
  f32x4 sMa[2][2], sCa[2][2];
  #pragma unroll
  for(int rt=0;rt<2;rt++){ sMa[rt][0]=vz; sMa[rt][1]=vz; sCa[rt][0]=vz; sCa[rt][1]=vz; }
  #pragma unroll
  for(int h=0;h<2;h++){
    // ---- T_half = X[64h:64h+64][:] * W (raw; scl/shift applied at S1 store)
    f32x4 tM[2][2], tC[2][2];
    #pragma unroll
    for(int rt=0;rt<2;rt++){ tM[rt][0]=vz; tM[rt][1]=vz; tC[rt][0]=vz; tC[rt][1]=vz; }
    for(int ks=0;ks<4;ks++){
      h16x8 xah[2], xal[2];
      #pragma unroll
      for(int rt=0;rt<2;rt++){
        const float* px=Xb+(size_t)(64*h+rb+16*rt+lr)*128+ks*32+lg*8;
        float4 u0=ld4(px), u1=ld4(px+4);
        float uv[8]={u0.x,u0.y,u0.z,u0.w,u1.x,u1.y,u1.z,u1.w};
        #pragma unroll
        for(int e=0;e<8;e++){ h16 hh,ll; split2(uv[e],hh,ll); xah[rt][e]=hh; xal[rt][e]=ll; }
      }
      __builtin_amdgcn_s_setprio(1);
      #pragma unroll
      for(int ct=0;ct<2;ct++){
        h16x8 bh=frag_ld2(Wph, cb+16*ct+lr, ks, lg);
        h16x8 bl=frag_ld2(Wpl, cb+16*ct+lr, ks, lg);
        #pragma unroll
        for(int rt=0;rt<2;rt++){
          tM[rt][ct]=__builtin_amdgcn_mfma_f32_16x16x32_f16(xah[rt],bh,tM[rt][ct],0,0,0);
          tC[rt][ct]=__builtin_amdgcn_mfma_f32_16x16x32_f16(xal[rt],bh,tC[rt][ct],0,0,0);
          tC[rt][ct]=__builtin_amdgcn_mfma_f32_16x16x32_f16(xah[rt],bl,tC[rt][ct],0,0,0);
        }
      }
      __builtin_amdgcn_s_setprio(0);
    }
    __syncthreads();        // h=1: prior phase-1b reads of T_half done
    #pragma unroll
    for(int rt=0;rt<2;rt++){   // store T_half planes (transposed, 64x64 eoff)
      int i0=rb+16*rt+lg*4;
      #pragma unroll
      for(int ct=0;ct<2;ct++){
        int j=cb+16*ct+lr;
        h16x4 h4,l4;
        #pragma unroll
        for(int r=0;r<4;r++){
          float x=tM[rt][ct][r]+tC[rt][ct][r]*SPLIT_R;
          h16 hh,ll; split2(x,hh,ll); h4[r]=hh; l4[r]=ll;
        }
        int off=(j*128+i0*2)^((j&7)<<4);
        *(h16x4*)((char*)Thh+off)=h4;
        *(h16x4*)((char*)Thl+off)=l4;
      }
    }
    __syncthreads();
    // ---- S1 += W[64h:64h+64][:]^T * T_half  (contraction over m-local)
    __builtin_amdgcn_s_setprio(1);
    #pragma unroll
    for(int ks2=0;ks2<2;ks2++){
      int ksW=2*h+ks2;
      h16x8 ah2[2],al2[2];
      #pragma unroll
      for(int rt=0;rt<2;rt++){
        ah2[rt]=frag_ld2(Wph, rb+16*rt+lr, ksW, lg);
        al2[rt]=frag_ld2(Wpl, rb+16*rt+lr, ksW, lg);
      }
      #pragma unroll
      for(int ct=0;ct<2;ct++){
        h16x8 bh=frag_ld(Thh, cb+16*ct+lr, ks2, lg);
        h16x8 bl=frag_ld(Thl, cb+16*ct+lr, ks2, lg);
        #pragma unroll
        for(int rt=0;rt<2;rt++){
          sMa[rt][ct]=__builtin_amdgcn_mfma_f32_16x16x32_f16(ah2[rt],bh,sMa[rt][ct],0,0,0);
          sCa[rt][ct]=__builtin_amdgcn_mfma_f32_16x16x32_f16(al2[rt],bh,sCa[rt][ct],0,0,0);
          sCa[rt][ct]=__builtin_amdgcn_mfma_f32_16x16x32_f16(ah2[rt],bl,sCa[rt][ct],0,0,0);
        }
      }
    }
    __builtin_amdgcn_s_setprio(0);
  }
  f32x4 accS[2][2];
  #pragma unroll
  for(int rt=0;rt<2;rt++)
    #pragma unroll
    for(int ct=0;ct<2;ct++) accS[rt][ct]=sMa[rt][ct]+sCa[rt][ct]*SPLIT_R;
  __syncthreads();                 // all W/T reads done before slot reuse
  st_gl(S1g+(size_t)b*4096, accS, lane,wv, scl, shift);   // S1 = scl*M0+shift*I
  h16* Ah=(h16*)lds;          h16* Al=Ah+4096;
  h16* Xh=(h16*)(lds+16384);  h16* Xl=Xh+4096;
  h16* Th=(h16*)(lds+32768);  h16* Tl=Th+4096;
  stS(Ah,Al,accS,dI,lane,wv, scl, shift + C1);            // A = S1 + C1*I
  __syncthreads();
  f32x4 aL[2][2];
  h16* parkh=(h16*)(R2+(size_t)b*4096);
  logm4<4,15,1>(Ah,Al,Xh,Xl,Th,Tl,parkh,red,dI, C1, tid,lane,wv, aL);
  __syncthreads();
  st_gl(R2+(size_t)b*4096, aL, lane,wv, 2.f, LNC1);       // L1 = 2 P R + ln(c) I
}

// column-mean over batch (unchanged)
__global__ __launch_bounds__(256) void kRed(const float* __restrict__ R2, float* outM, float scale){
  __shared__ float red[256];
  int tid=threadIdx.x; int ee=tid&31; int sl=tid>>5;
  int e0 = blockIdx.x*32 + ee;
  float s=0.f;
  for(int j=0;j<256;j++) s += R2[(size_t)(sl+8*j)*4096 + e0];
  red[tid]=s; __syncthreads();
  if (sl<4) red[tid]+=red[tid+128];
  __syncthreads();
  if (sl<2) red[tid]+=red[tid+64];
  __syncthreads();
  if (sl==0) outM[e0] = (red[tid]+red[tid+32])*scale;
}

// G0^{+-1/2} = exp(+-Lbar/2); Bs = sqrt(sym(bn_bias))
__global__ __launch_bounds__(256) void kB(const float* Lbar, const float* biasP,
     float* Gi0, float* Gs0, float* Bs){
  __shared__ __align__(16) char lds[50176];
  int tid=threadIdx.x, lane=tid&63, wv=tid>>6;
  DECL_DI(dI);
  h16* s0h=(h16*)lds;          h16* s0l=s0h+4096;
  h16* s1h=(h16*)(lds+16384);  h16* s1l=s1h+4096;
  h16* s2h=(h16*)(lds+32768);  h16* s2l=s2h+4096;
  float* red=(float*)(lds+49152);
  float tr = block_sum((tid<64)? Lbar[tid*65]:0.f, red, tid);
  float cb_ = tr*(1.f/64.f);
  fill_gl(s0h,s0l, Lbar, 0.5f, -cb_, tid);                // +D/2
  __syncthreads();
  exp4(s0h,s0l,s1h,s1l,s2h,s2l, dI, 1.f, tid,lane,wv);    // exp(D/2) in s0
  plane_out(s0h,s0l, Gs0, expf(0.5f*cb_), tid);
  __syncthreads();
  fill_gl(s0h,s0l, Lbar, -0.5f, -cb_, tid);               // -D/2
  __syncthreads();
  exp4(s0h,s0l,s1h,s1l,s2h,s2l, dI, 1.f, tid,lane,wv);    // exp(-D/2) in s0
  plane_out(s0h,s0l, Gi0, expf(-0.5f*cb_), tid);
  __syncthreads();
  float tb = block_sum((tid<64)? biasP[tid*65]:0.f, red, tid);
  float itb=1.f/tb;
  { // Y = sym(bias)/tb -> s0
    int r=tid>>2;
    #pragma unroll
    for(int q=0;q<4;q++){
      int c4=(tid&3)*16+q*4;
      float4 v=ld4(biasP + r*64 + c4);
      float vv[4]={v.x,v.y,v.z,v.w};
      h16x4 h4,l4;
      #pragma unroll
      for(int j=0;j<4;j++){
        float x = 0.5f*(vv[j] + biasP[(c4+j)*64 + r]) * itb;
        h16 hh,ll; split2(x,hh,ll); h4[j]=hh; l4[j]=ll;
      }
      h4_st(s0h,r,c4,h4); h4_st(s0l,r,c4,l4);
    }
  }
  __syncthreads();
  ns_sqrt3(s0h,s0l,s1h,s1l,s2h,s2l, dI, tid,lane,wv);
  plane_out(s0h,s0l, Bs, sqrtf(tb), tid);
}

// Karcher-step log: M = Gi S1 Gi ; L = logm(M) -> R2 ; optional v accumulation
__global__ __launch_bounds__(256,3) void kC(const float* __restrict__ S1g, const float* GiP,
     float* R2, float* vpart, int doV){
  __shared__ __align__(16) char lds[50176];
  int tid=threadIdx.x, b=blockIdx.x, lane=tid&63, wv=tid>>6;
  DECL_DI(dI);
  h16* s0h=(h16*)lds;          h16* s0l=s0h+4096;
  h16* s1h=(h16*)(lds+16384);  h16* s1l=s1h+4096;
  h16* s2h=(h16*)(lds+32768);  h16* s2l=s2h+4096;
  float* red=(float*)(lds+49152);
  fill_gl(s0h,s0l, S1g+(size_t)b*4096, 1.f,0.f, tid);
  fill_gl(s1h,s1l, GiP, 1.f,0.f, tid);
  __syncthreads();
  f32x4 acc[2][2];
  mmT<1,1,0>(s0h,s0l,s1h,s1l,0,acc,lane,wv);              // S1 Gi
  stS(s2h,s2l,acc,dI,lane,wv,1.f,0.f); __syncthreads();
  mmT<1,1,0>(s1h,s1l,s2h,s2l,0,acc,lane,wv);              // M = Gi S1 Gi
  stS(s0h,s0l,acc,dI,lane,wv,1.f,1.f); __syncthreads();   // A = M + I
  f32x4 aL[2][2];
  h16* parkh=(h16*)(R2+(size_t)b*4096);
  logm4<8,30,2>(s0h,s0l,s1h,s1l,s2h,s2l,parkh,red,dI, 1.f, tid,lane,wv, aL);
  __syncthreads();
  st_gl(R2+(size_t)b*4096, aL, lane,wv, 2.f, 0.f);
  if (doV){
    float s=0.f;
    #pragma unroll
    for(int rt=0;rt<2;rt++)
      #pragma unroll
      for(int ct=0;ct<2;ct++)
        #pragma unroll
        for(int r=0;r<4;r++){ float lv=2.f*aL[rt][ct][r]; s=fmaf(lv,lv,s); }
    __syncthreads();
    s = block_sum(s, red, tid);
    if (tid==0) atomicAdd(vpart + (b&31), s);
  }
}

// G_new = Gs exp(Ebar) Gs ; then G_new^{+-1/2}
__global__ __launch_bounds__(256) void kD(const float* Ebar, const float* GsP,
     float* GsN, float* GiN){
  __shared__ __align__(16) char lds[50176];
  int tid=threadIdx.x, lane=tid&63, wv=tid>>6;
  DECL_DI(dI);
  h16* s0h=(h16*)lds;          h16* s0l=s0h+4096;
  h16* s1h=(h16*)(lds+16384);  h16* s1l=s1h+4096;
  h16* s2h=(h16*)(lds+32768);  h16* s2l=s2h+4096;
  float* red=(float*)(lds+49152);
  fill_gl(s0h,s0l, Ebar, 1.f,0.f, tid); __syncthreads();
  exp4(s0h,s0l,s1h,s1l,s2h,s2l, dI, 1.f, tid,lane,wv);    // E in s0
  fill_gl(s1h,s1l, GsP, 1.f,0.f, tid);                    // s1 dead after exp4
  __syncthreads();
  f32x4 acc[2][2];
  mmT<1,1,0>(s0h,s0l,s1h,s1l,0,acc,lane,wv);              // E Gs -> s2
  stS(s2h,s2l,acc,dI,lane,wv,1.f,0.f); __syncthreads();
  mmT<1,1,0>(s1h,s1l,s2h,s2l,0,acc,lane,wv);              // G = Gs (E Gs)
  float tv=0.f;
  #pragma unroll
  for(int rt=0;rt<2;rt++)
    #pragma unroll
    for(int ct=0;ct<2;ct++)
      #pragma unroll
      for(int r=0;r<4;r++) tv += acc[rt][ct][r]*dI[rt][ct][r];
  float t = block_sum(tv, red, tid);
  stS(s0h,s0l,acc,dI,lane,wv,1.f/t,0.f); __syncthreads(); // Y = G/t -> s0
  ns_sqrt3(s0h,s0l,s1h,s1l,s2h,s2l, dI, tid,lane,wv);
  float st_=sqrtf(t), ist=1.f/st_;
  plane_out(s0h,s0l, GsN, st_, tid);
  plane_out(s1h,s1l, GiN, ist, tid);
}

__global__ void kF2(const float* vpart, const float* gammaP, float* sOut){
  if (threadIdx.x==0 && blockIdx.x==0){
    float v=0.f;
    for(int i=0;i<32;i++) v+=vpart[i];
    v *= (1.f/2048.f);
    sOut[0] = gammaP[0] / sqrtf(v + 1e-5f);
  }
}

// Y=exp(s Lt); Z=Bs Y Bs; Lg=logm(Z); out = triu(Lg)*coef @ Wc^T + bc
__global__ __launch_bounds__(256,3) void kG(float* R2, const float* BsP, const float* sP,
     const float* __restrict__ WcP, const float* bcP, float* outP){
  __shared__ __align__(16) char lds[50176];
  int tid=threadIdx.x, b=blockIdx.x, lane=tid&63, wv=tid>>6;
  DECL_DI(dI);
  h16* s0h=(h16*)lds;          h16* s0l=s0h+4096;
  h16* s1h=(h16*)(lds+16384);  h16* s1l=s1h+4096;
  h16* s2h=(h16*)(lds+32768);  h16* s2l=s2h+4096;
  float* red=(float*)(lds+49152);
  fill_gl(s0h,s0l, R2+(size_t)b*4096, 1.f,0.f, tid); __syncthreads();  // Lt
  float s = sP[0];
  exp4(s0h,s0l,s1h,s1l,s2h,s2l, dI, s, tid,lane,wv);      // Y in s0
  fill_gl(s1h,s1l, BsP, 1.f,0.f, tid);                    // s1 dead after exp4
  __syncthreads();
  f32x4 acc[2][2];
  mmT<1,1,0>(s0h,s0l,s1h,s1l,0,acc,lane,wv);              // Y Bs -> s2
  stS(s2h,s2l,acc,dI,lane,wv,1.f,0.f); __syncthreads();
  mmT<1,1,0>(s1h,s1l,s2h,s2l,0,acc,lane,wv);              // Z = Bs Y Bs
  stS(s0h,s0l,acc,dI,lane,wv,1.f,1.f); __syncthreads();   // A = Z + I -> s0
  f32x4 aL[2][2];
  h16* parkh=(h16*)(R2+(size_t)b*4096);
  logm4<4,15,2>(s0h,s0l,s1h,s1l,s2h,s2l,parkh,red,dI, 1.f, tid,lane,wv, aL);
  // epilogue: triu(2*P*R) * coef @ Wc^T
  float o0=0,o1=0,o2=0,o3=0;
  {
    int lr=lane&15, lq=lane>>4, rb=(wv&1)*32, cb=(wv>>1)*32;
    #pragma unroll
    for(int rt=0;rt<2;rt++)
      #pragma unroll
      for(int ct=0;ct<2;ct++)
        #pragma unroll
        for(int r=0;r<4;r++){
          int i=rb+16*rt+lq*4+r, j=cb+16*ct+lr;
          float lg2=2.f*aL[rt][ct][r];
          int a=(i<j)? i:j, bb=(i<j)? j:i;
          int tri = a*64 - ((a*(a-1))>>1) + (bb-a);
          float w = (i==j)? lg2 : lg2*0.70710678118654752f;
          o0=fmaf(w, WcP[tri],      o0);
          o1=fmaf(w, WcP[2080+tri], o1);
          o2=fmaf(w, WcP[4160+tri], o2);
          o3=fmaf(w, WcP[6240+tri], o3);
        }
  }
  __syncthreads();
  float* redv=(float*)lds;
  float4 pk; pk.x=o0; pk.y=o1; pk.z=o2; pk.w=o3;
  st4(redv+4*tid, pk); __syncthreads();
  for(int off=128; off>0; off>>=1){
    if (tid<off){
      float4 x=ld4(redv+4*tid), y=ld4(redv+4*(tid+off));
      x.x+=y.x; x.y+=y.y; x.z+=y.z; x.w+=y.w;
      st4(redv+4*tid, x);
    }
    __syncthreads();
  }
  if (tid==0){
    outP[b*4+0]=redv[0]+bcP[0];
    outP[b*4+1]=redv[1]+bcP[1];
    outP[b*4+2]=redv[2]+bcP[2];
    outP[b*4+3]=redv[3]+bcP[3];
  }
}

extern "C" void kernel_launch(void* const* d_in, const int* in_sizes, int n_in,
                              void* d_out, int out_size, void* d_ws, size_t ws_size,
                              hipStream_t stream){
  const float* X     = (const float*)d_in[0];
  const float* alpha = (const float*)d_in[1];
  const float* W     = (const float*)d_in[2];
  const float* gamma = (const float*)d_in[3];
  const float* bias  = (const float*)d_in[4];
  const float* Wc    = (const float*)d_in[5];
  const float* bc    = (const float*)d_in[6];
  float* ws = (float*)d_ws;
  float* S1 = ws + WS_S1;
  float* R2 = ws + WS_R2;
  float* sm = ws + WS_SM;

  hipMemsetAsync(sm + SM_VPART, 0, 33*sizeof(float), stream);

  kA  <<<2048,256,0,stream>>>(X, alpha, W, S1, R2);
  kRed<<<128, 256,0,stream>>>(R2, sm+SM_LBAR, 1.f/2048.f);
  kB  <<<1,   256,0,stream>>>(sm+SM_LBAR, bias, sm+SM_GI0, sm+SM_GS0, sm+SM_BS);
  kC  <<<2048,256,0,stream>>>(S1, sm+SM_GI0, R2, nullptr, 0);
  kRed<<<128, 256,0,stream>>>(R2, sm+SM_EBAR1, 1.f/2048.f);
  kD  <<<1,   256,0,stream>>>(sm+SM_EBAR1, sm+SM_GS0, sm+SM_GS1, sm+SM_GI1);
  kC  <<<2048,256,0,stream>>>(S1, sm+SM_GI1, R2, nullptr, 0);
  kRed<<<128, 256,0,stream>>>(R2, sm+SM_EBAR2, 1.f/2048.f);
  kD  <<<1,   256,0,stream>>>(sm+SM_EBAR2, sm+SM_GS1, sm+SM_GS2, sm+SM_GI2);
  kC  <<<2048,256,0,stream>>>(S1, sm+SM_GI2, R2, sm+SM_VPART, 1);
  kF2 <<<1,1,0,stream>>>(sm+SM_VPART, gamma, sm+SM_S);
  kG  <<<2048,256,0,stream>>>(R2, sm+SM_BS, sm+SM_S, Wc, bc, (float*)d_out);
}